// Round 13
// baseline (562.221 us; speedup 1.0000x reference)
//
#include <hip/hip_runtime.h>

#define DEVINL __device__ __forceinline__

typedef __bf16 bf16x8 __attribute__((ext_vector_type(8)));
typedef float f32x4 __attribute__((ext_vector_type(4)));
typedef unsigned short u16x4 __attribute__((ext_vector_type(4)));

static constexpr int Bb = 4, S = 2048, H = 1024, NH = 16, DK = 64, FF = 4096;
static constexpr int Mrows = Bb * S; // 8192
static constexpr int QS = 3 * H;    // fused QKV row stride

DEVINL unsigned short f2bf(float f) {
    union { __bf16 b; unsigned short u; } r;
    r.b = (__bf16)f;
    return r.u;
}

DEVINL unsigned pack_bf2(float a, float b) {
    union { __bf16 h[2]; unsigned u; } r;
    r.h[0] = (__bf16)a; r.h[1] = (__bf16)b;
    return r.u;
}

DEVINL void gld16(const void* g, void* l) {
    auto gp = reinterpret_cast<const __attribute__((address_space(1))) unsigned*>(
        reinterpret_cast<unsigned long long>(g));
    auto lp = reinterpret_cast<__attribute__((address_space(3))) unsigned*>(
        (unsigned)reinterpret_cast<unsigned long long>(l));
    __builtin_amdgcn_global_load_lds(gp, lp, 16, 0, 0);
}

// ---------------- merged weight convert: all 6 weights, one launch ----------
// f32 W[K][N] -> bf16 Wt[N][K]; qkv outputs land contiguously at Wqt.
__global__ __launch_bounds__(256)
void wcvt_all(const float* __restrict__ Wq, const float* __restrict__ Wk,
              const float* __restrict__ Wv, const float* __restrict__ Wo,
              const float* __restrict__ W1, const float* __restrict__ W2,
              unsigned short* __restrict__ Wqt, unsigned short* __restrict__ Wot,
              unsigned short* __restrict__ W1t, unsigned short* __restrict__ W2t) {
    int id = blockIdx.x;
    const float* in; unsigned short* out; int K, N;
    if (id < 3072) {
        int which = id >> 10; id &= 1023;
        in = which == 0 ? Wq : (which == 1 ? Wk : Wv);
        out = Wqt + (size_t)which * H * H; K = H; N = H;
    } else if (id < 4096) { in = Wo; out = Wot; K = H; N = H; id -= 3072; }
    else if (id < 8192)   { in = W1; out = W1t; K = H; N = FF; id -= 4096; }
    else                  { in = W2; out = W2t; K = FF; N = H; id -= 8192; }
    const int nx = N / 32;
    const int n0 = (id % nx) * 32, k0 = (id / nx) * 32;

    __shared__ float t[32][33];
    int tx = threadIdx.x, ty = threadIdx.y;
#pragma unroll
    for (int i = 0; i < 32; i += 8) t[ty + i][tx] = in[(size_t)(k0 + ty + i) * N + n0 + tx];
    __syncthreads();
#pragma unroll
    for (int i = 0; i < 32; i += 8) out[(size_t)(n0 + ty + i) * K + k0 + tx] = f2bf(t[tx][ty + i]);
}

// ---------------- fuse q/k/v bias into one [3072] array ----------------
__global__ __launch_bounds__(256)
void catbias(const float* __restrict__ a, const float* __restrict__ b,
             const float* __restrict__ c, float* __restrict__ o) {
    int i = blockIdx.x * 256 + threadIdx.x;
    float v = (i < 1024) ? a[i] : (i < 2048 ? b[i - 1024] : c[i - 2048]);
    o[i] = v;
}

// ---------------- LayerNorm: f32 row -> bf16 row ----------------
__global__ __launch_bounds__(256)
void ln_kernel(const float* __restrict__ x, const float* __restrict__ g,
               const float* __restrict__ be, unsigned short* __restrict__ y) {
    int row = blockIdx.x, tid = threadIdx.x;
    const float4 v = ((const float4*)(x + (size_t)row * H))[tid];
    float s = v.x + v.y + v.z + v.w;
    float ss = v.x * v.x + v.y * v.y + v.z * v.z + v.w * v.w;
#pragma unroll
    for (int m = 1; m < 64; m <<= 1) { s += __shfl_xor(s, m); ss += __shfl_xor(ss, m); }
    __shared__ float red[2][4];
    int lane = tid & 63, w = tid >> 6;
    if (lane == 0) { red[0][w] = s; red[1][w] = ss; }
    __syncthreads();
    s = red[0][0] + red[0][1] + red[0][2] + red[0][3];
    ss = red[1][0] + red[1][1] + red[1][2] + red[1][3];
    float mean = s * (1.f / H);
    float var = ss * (1.f / H) - mean * mean;
    float rstd = rsqrtf(var + 1e-5f);
    float4 gv = ((const float4*)g)[tid];
    float4 bv = ((const float4*)be)[tid];
    ushort4 o;
    o.x = f2bf((v.x - mean) * rstd * gv.x + bv.x);
    o.y = f2bf((v.y - mean) * rstd * gv.y + bv.y);
    o.z = f2bf((v.z - mean) * rstd * gv.z + bv.z);
    o.w = f2bf((v.w - mean) * rstd * gv.w + bv.w);
    ((ushort4*)(y + (size_t)row * H))[tid] = o;
}

// ---------------- 256x256 8-phase GEMM (T2+T3+T4+T5), quadrant schedule ------
// EPI: 0 = store bf16, 1 = gelu->bf16
template <int EPI>
__global__ __launch_bounds__(512, 2)
void gemm8p(const unsigned short* __restrict__ A, const unsigned short* __restrict__ Bt,
            const float* __restrict__ bias, void* __restrict__ outp, int N, int K) {
    __shared__ __align__(16) char lds[131072];
    const int tid = threadIdx.x, lane = tid & 63, w = tid >> 6;
    const int wm = w >> 2, wn = w & 3;
    const int fr = lane & 15, fq = lane >> 4;
    const int nwg = gridDim.x, id = blockIdx.x;
    const int swz = (id & 7) * (nwg >> 3) + (id >> 3);
    const int m0 = (swz & 31) * 256, n0 = (swz >> 5) * 256;

    int srow[2], scol[2];
#pragma unroll
    for (int l = 0; l < 2; ++l) {
        int idx = l * 512 + tid;
        srow[l] = idx >> 3;
        scol[l] = ((idx & 7) ^ (srow[l] & 7)) * 8;
    }
    const int NT = K >> 6;

    auto stage = [&](int ht, int buf, int kt) {
        const unsigned short* src = (ht < 2) ? A : Bt;
        const int hh = ht & 1;
        char* dst = lds + ((ht < 2 ? 0 : 65536) + (buf * 2 + hh) * 16384);
        const int rbase = ((ht < 2) ? m0 : n0) + hh * 128;
        const int kb = kt * 64;
#pragma unroll
        for (int l = 0; l < 2; ++l)
            gld16(src + (size_t)(rbase + srow[l]) * K + kb + scol[l],
                  dst + (size_t)(l * 512 + tid) * 16);
    };

    int oa[2];
#pragma unroll
    for (int ks = 0; ks < 2; ++ks)
        oa[ks] = fr * 128 + (((ks * 4 + fq) ^ (fr & 7)) & 7) * 16;
    const int aBase0 = wm * 16384;
    const int bBase0 = 65536 + (wn >> 1) * 16384 + (wn & 1) * 8192;

    f32x4 acc[8][4] = {};
    bf16x8 aF[4][2], bF[4][2];

    stage(0, 0, 0); stage(1, 0, 0); stage(2, 0, 0); stage(3, 0, 0);
    if (NT > 1) {
        stage(0, 1, 1);
        asm volatile("s_waitcnt vmcnt(2)" ::: "memory");
    } else {
        asm volatile("s_waitcnt vmcnt(0)" ::: "memory");
    }
    __builtin_amdgcn_s_barrier();

    int buf = 0;
    for (int t = 0; t < NT; ++t, buf ^= 1) {
        const char* Ar = lds + aBase0 + buf * 32768;
        const char* Br = lds + bBase0 + buf * 32768;

#pragma unroll
        for (int mb = 0; mb < 4; ++mb)
#pragma unroll
            for (int ks = 0; ks < 2; ++ks)
                aF[mb][ks] = *(const bf16x8*)(Ar + mb * 2048 + oa[ks]);
#pragma unroll
        for (int nb = 0; nb < 2; ++nb)
#pragma unroll
            for (int ks = 0; ks < 2; ++ks)
                bF[nb][ks] = *(const bf16x8*)(Br + nb * 2048 + oa[ks]);
        if (t + 1 < NT) stage(1, buf ^ 1, t + 1);
        __builtin_amdgcn_s_barrier();
        asm volatile("s_waitcnt lgkmcnt(0)" ::: "memory");
        __builtin_amdgcn_sched_barrier(0);
        __builtin_amdgcn_s_setprio(1);
#pragma unroll
        for (int mb = 0; mb < 4; ++mb)
#pragma unroll
            for (int nb = 0; nb < 2; ++nb)
#pragma unroll
                for (int ks = 0; ks < 2; ++ks)
                    acc[mb][nb] = __builtin_amdgcn_mfma_f32_16x16x32_bf16(aF[mb][ks], bF[nb][ks], acc[mb][nb], 0, 0, 0);
        __builtin_amdgcn_s_setprio(0);
        __builtin_amdgcn_s_barrier();

#pragma unroll
        for (int nb = 2; nb < 4; ++nb)
#pragma unroll
            for (int ks = 0; ks < 2; ++ks)
                bF[nb][ks] = *(const bf16x8*)(Br + nb * 2048 + oa[ks]);
        if (t + 1 < NT) stage(2, buf ^ 1, t + 1);
        __builtin_amdgcn_s_barrier();
        asm volatile("s_waitcnt lgkmcnt(0)" ::: "memory");
        __builtin_amdgcn_sched_barrier(0);
        __builtin_amdgcn_s_setprio(1);
#pragma unroll
        for (int mb = 0; mb < 4; ++mb)
#pragma unroll
            for (int nb = 2; nb < 4; ++nb)
#pragma unroll
                for (int ks = 0; ks < 2; ++ks)
                    acc[mb][nb] = __builtin_amdgcn_mfma_f32_16x16x32_bf16(aF[mb][ks], bF[nb][ks], acc[mb][nb], 0, 0, 0);
        __builtin_amdgcn_s_setprio(0);
        __builtin_amdgcn_s_barrier();

#pragma unroll
        for (int mb = 0; mb < 4; ++mb)
#pragma unroll
            for (int ks = 0; ks < 2; ++ks)
                aF[mb][ks] = *(const bf16x8*)(Ar + 8192 + mb * 2048 + oa[ks]);
        if (t + 1 < NT) stage(3, buf ^ 1, t + 1);
        __builtin_amdgcn_s_barrier();
        asm volatile("s_waitcnt lgkmcnt(0)" ::: "memory");
        __builtin_amdgcn_sched_barrier(0);
        __builtin_amdgcn_s_setprio(1);
#pragma unroll
        for (int mb = 0; mb < 4; ++mb)
#pragma unroll
            for (int nb = 0; nb < 2; ++nb)
#pragma unroll
                for (int ks = 0; ks < 2; ++ks)
                    acc[4 + mb][nb] = __builtin_amdgcn_mfma_f32_16x16x32_bf16(aF[mb][ks], bF[nb][ks], acc[4 + mb][nb], 0, 0, 0);
        __builtin_amdgcn_s_setprio(0);
        __builtin_amdgcn_s_barrier();

        if (t + 2 < NT) {
            stage(0, buf, t + 2);
            asm volatile("s_waitcnt vmcnt(2)" ::: "memory");
        } else if (t + 1 < NT) {
            asm volatile("s_waitcnt vmcnt(0)" ::: "memory");
        }
        __builtin_amdgcn_s_barrier();
        __builtin_amdgcn_s_setprio(1);
#pragma unroll
        for (int mb = 0; mb < 4; ++mb)
#pragma unroll
            for (int nb = 2; nb < 4; ++nb)
#pragma unroll
                for (int ks = 0; ks < 2; ++ks)
                    acc[4 + mb][nb] = __builtin_amdgcn_mfma_f32_16x16x32_bf16(aF[mb][ks], bF[nb][ks], acc[4 + mb][nb], 0, 0, 0);
        __builtin_amdgcn_s_setprio(0);
        __builtin_amdgcn_s_barrier();
    }

#pragma unroll
    for (int mb = 0; mb < 8; ++mb) {
        int row0 = m0 + wm * 128 + mb * 16 + fq * 4;
#pragma unroll
        for (int nb = 0; nb < 4; ++nb) {
            int col = n0 + wn * 64 + nb * 16 + fr;
            float bz = bias[col];
#pragma unroll
            for (int j = 0; j < 4; ++j) {
                float vv = acc[mb][nb][j] + bz;
                size_t idx = (size_t)(row0 + j) * N + col;
                if (EPI == 0) {
                    ((unsigned short*)outp)[idx] = f2bf(vv);
                } else {
                    float tg = 0.5f * vv * (1.f + erff(vv * 0.70710678118654752f));
                    ((unsigned short*)outp)[idx] = f2bf(tg);
                }
            }
        }
    }
}

// ---------------- 128x256 8-phase GEMM (QKV) ---------------------------------
// EPI: 0 = bf16 + bias; 2 = f32 + bias + resid
template <int EPI>
__global__ __launch_bounds__(512, 2)
void gemm8p128(const unsigned short* __restrict__ A, const unsigned short* __restrict__ Bt,
               const float* __restrict__ bias, const float* __restrict__ resid,
               void* __restrict__ outp, int N, int K) {
    __shared__ __align__(16) char lds[98304];
    const int tid = threadIdx.x, lane = tid & 63, w = tid >> 6;
    const int wm = w >> 2, wn = w & 3;
    const int fr = lane & 15, fq = lane >> 4;
    const int nwg = gridDim.x, id = blockIdx.x;
    const int swz = (id & 7) * (nwg >> 3) + (id >> 3);
    const int m0 = (swz & 63) * 128, n0 = (swz >> 6) * 256;

    int srow[2], scol[2];
#pragma unroll
    for (int l = 0; l < 2; ++l) {
        int idx = l * 512 + tid;
        srow[l] = idx >> 3;
        scol[l] = ((idx & 7) ^ (srow[l] & 7)) * 8;
    }
    const int NT = K >> 6;

    auto stageA = [&](int buf, int kt) {
        char* dst = lds + buf * 16384;
#pragma unroll
        for (int l = 0; l < 2; ++l)
            gld16(A + (size_t)(m0 + srow[l]) * K + kt * 64 + scol[l],
                  dst + (size_t)(l * 512 + tid) * 16);
    };
    auto stageB = [&](int hh, int buf, int kt) {
        char* dst = lds + 32768 + buf * 32768 + hh * 16384;
#pragma unroll
        for (int l = 0; l < 2; ++l)
            gld16(Bt + (size_t)(n0 + hh * 128 + srow[l]) * K + kt * 64 + scol[l],
                  dst + (size_t)(l * 512 + tid) * 16);
    };

    int oa[2];
#pragma unroll
    for (int ks = 0; ks < 2; ++ks)
        oa[ks] = fr * 128 + (((ks * 4 + fq) ^ (fr & 7)) & 7) * 16;
    const int aWB = wm * 8192;
    const int bWB = (wn >> 1) * 16384 + (wn & 1) * 8192;

    f32x4 acc[4][4] = {};
    bf16x8 aF[2][2], bF[4][2];

    stageA(0, 0); stageB(0, 0, 0); stageB(1, 0, 0);
    if (NT > 1) {
        stageA(1, 1);
        asm volatile("s_waitcnt vmcnt(2)" ::: "memory");
    } else {
        asm volatile("s_waitcnt vmcnt(0)" ::: "memory");
    }
    __builtin_amdgcn_s_barrier();

    int buf = 0;
    for (int t = 0; t < NT; ++t, buf ^= 1) {
        const char* Ar = lds + buf * 16384 + aWB;
        const char* Br = lds + 32768 + buf * 32768 + bWB;

#pragma unroll
        for (int mb = 0; mb < 2; ++mb)
#pragma unroll
            for (int ks = 0; ks < 2; ++ks)
                aF[mb][ks] = *(const bf16x8*)(Ar + mb * 2048 + oa[ks]);
#pragma unroll
        for (int nb = 0; nb < 2; ++nb)
#pragma unroll
            for (int ks = 0; ks < 2; ++ks)
                bF[nb][ks] = *(const bf16x8*)(Br + nb * 2048 + oa[ks]);
        if (t + 1 < NT) stageB(0, buf ^ 1, t + 1);
        __builtin_amdgcn_s_barrier();
        asm volatile("s_waitcnt lgkmcnt(0)" ::: "memory");
        __builtin_amdgcn_sched_barrier(0);
        __builtin_amdgcn_s_setprio(1);
#pragma unroll
        for (int mb = 0; mb < 2; ++mb)
#pragma unroll
            for (int nb = 0; nb < 2; ++nb)
#pragma unroll
                for (int ks = 0; ks < 2; ++ks)
                    acc[mb][nb] = __builtin_amdgcn_mfma_f32_16x16x32_bf16(aF[mb][ks], bF[nb][ks], acc[mb][nb], 0, 0, 0);
        __builtin_amdgcn_s_setprio(0);
        __builtin_amdgcn_s_barrier();

#pragma unroll
        for (int nb = 2; nb < 4; ++nb)
#pragma unroll
            for (int ks = 0; ks < 2; ++ks)
                bF[nb][ks] = *(const bf16x8*)(Br + nb * 2048 + oa[ks]);
        if (t + 1 < NT) stageB(1, buf ^ 1, t + 1);
        __builtin_amdgcn_s_barrier();
        asm volatile("s_waitcnt lgkmcnt(0)" ::: "memory");
        __builtin_amdgcn_sched_barrier(0);
        __builtin_amdgcn_s_setprio(1);
#pragma unroll
        for (int mb = 0; mb < 2; ++mb)
#pragma unroll
            for (int nb = 2; nb < 4; ++nb)
#pragma unroll
                for (int ks = 0; ks < 2; ++ks)
                    acc[mb][nb] = __builtin_amdgcn_mfma_f32_16x16x32_bf16(aF[mb][ks], bF[nb][ks], acc[mb][nb], 0, 0, 0);
        __builtin_amdgcn_s_setprio(0);
        __builtin_amdgcn_s_barrier();

#pragma unroll
        for (int mb = 0; mb < 2; ++mb)
#pragma unroll
            for (int ks = 0; ks < 2; ++ks)
                aF[mb][ks] = *(const bf16x8*)(Ar + 4096 + mb * 2048 + oa[ks]);
        __builtin_amdgcn_s_barrier();
        asm volatile("s_waitcnt lgkmcnt(0)" ::: "memory");
        __builtin_amdgcn_sched_barrier(0);
        __builtin_amdgcn_s_setprio(1);
#pragma unroll
        for (int mb = 0; mb < 2; ++mb)
#pragma unroll
            for (int nb = 0; nb < 2; ++nb)
#pragma unroll
                for (int ks = 0; ks < 2; ++ks)
                    acc[2 + mb][nb] = __builtin_amdgcn_mfma_f32_16x16x32_bf16(aF[mb][ks], bF[nb][ks], acc[2 + mb][nb], 0, 0, 0);
        __builtin_amdgcn_s_setprio(0);
        __builtin_amdgcn_s_barrier();

        if (t + 2 < NT) {
            stageA(buf, t + 2);
            asm volatile("s_waitcnt vmcnt(2)" ::: "memory");
        } else if (t + 1 < NT) {
            asm volatile("s_waitcnt vmcnt(0)" ::: "memory");
        }
        __builtin_amdgcn_s_barrier();
        __builtin_amdgcn_s_setprio(1);
#pragma unroll
        for (int mb = 0; mb < 2; ++mb)
#pragma unroll
            for (int nb = 2; nb < 4; ++nb)
#pragma unroll
                for (int ks = 0; ks < 2; ++ks)
                    acc[2 + mb][nb] = __builtin_amdgcn_mfma_f32_16x16x32_bf16(aF[mb][ks], bF[nb][ks], acc[2 + mb][nb], 0, 0, 0);
        __builtin_amdgcn_s_setprio(0);
        __builtin_amdgcn_s_barrier();
    }

#pragma unroll
    for (int mb = 0; mb < 4; ++mb) {
        int row0 = m0 + wm * 64 + mb * 16 + fq * 4;
#pragma unroll
        for (int nb = 0; nb < 4; ++nb) {
            int col = n0 + wn * 64 + nb * 16 + fr;
            float bz = bias[col];
#pragma unroll
            for (int j = 0; j < 4; ++j) {
                size_t idx = (size_t)(row0 + j) * N + col;
                float vv = acc[mb][nb][j] + bz;
                if (EPI == 0) {
                    ((unsigned short*)outp)[idx] = f2bf(vv);
                } else {
                    ((float*)outp)[idx] = vv + resid[idx];
                }
            }
        }
    }
}

// ---------------- 128x128 GEMM, 64KB LDS -> 2 blocks/CU (Wo, FFN2) -----------
// EPI: 2 = f32 + bias + resid
template <int EPI>
__global__ __launch_bounds__(512, 4)
void gemm128(const unsigned short* __restrict__ A, const unsigned short* __restrict__ Bt,
             const float* __restrict__ bias, const float* __restrict__ resid,
             void* __restrict__ outp, int N, int K) {
    __shared__ __align__(16) char lds[65536]; // A[2][16KB] @0, B[2][16KB] @32768
    const int tid = threadIdx.x, lane = tid & 63, w = tid >> 6;
    const int wm = w >> 1, wn = w & 1;
    const int fr = lane & 15, fq = lane >> 4;
    const int nwg = gridDim.x, id = blockIdx.x;
    const int swz = (id & 7) * (nwg >> 3) + (id >> 3);
    const int m0 = (swz & 63) * 128, n0 = (swz >> 6) * 128;

    int srow[2], scol[2];
#pragma unroll
    for (int l = 0; l < 2; ++l) {
        int idx = l * 512 + tid;
        srow[l] = idx >> 3;
        scol[l] = ((idx & 7) ^ (srow[l] & 7)) * 8;
    }
    const int NT = K >> 6;

    auto stageA = [&](int buf, int kt) {
        char* dst = lds + buf * 16384;
#pragma unroll
        for (int l = 0; l < 2; ++l)
            gld16(A + (size_t)(m0 + srow[l]) * K + kt * 64 + scol[l],
                  dst + (size_t)(l * 512 + tid) * 16);
    };
    auto stageB = [&](int buf, int kt) {
        char* dst = lds + 32768 + buf * 16384;
#pragma unroll
        for (int l = 0; l < 2; ++l)
            gld16(Bt + (size_t)(n0 + srow[l]) * K + kt * 64 + scol[l],
                  dst + (size_t)(l * 512 + tid) * 16);
    };

    int oa[2];
#pragma unroll
    for (int ks = 0; ks < 2; ++ks)
        oa[ks] = fr * 128 + (((ks * 4 + fq) ^ (fr & 7)) & 7) * 16;
    const int aWB = wm * 4096; // 32 rows per wave-m
    const int bWB = wn * 8192; // 64 rows per wave-n

    f32x4 acc[2][4] = {};
    bf16x8 aF[2][2], bF[2][2];

    stageA(0, 0); stageB(0, 0);
    asm volatile("s_waitcnt vmcnt(0)" ::: "memory");
    __builtin_amdgcn_s_barrier();

    int buf = 0;
    for (int t = 0; t < NT; ++t, buf ^= 1) {
        const char* Ar = lds + buf * 16384 + aWB;
        const char* Br = lds + 32768 + buf * 16384 + bWB;

        // P1: all A frags + B nb0-1; stage A(t+1)
#pragma unroll
        for (int mb = 0; mb < 2; ++mb)
#pragma unroll
            for (int ks = 0; ks < 2; ++ks)
                aF[mb][ks] = *(const bf16x8*)(Ar + mb * 2048 + oa[ks]);
#pragma unroll
        for (int nb = 0; nb < 2; ++nb)
#pragma unroll
            for (int ks = 0; ks < 2; ++ks)
                bF[nb][ks] = *(const bf16x8*)(Br + nb * 2048 + oa[ks]);
        if (t + 1 < NT) stageA(buf ^ 1, t + 1);
        __builtin_amdgcn_s_barrier();
        asm volatile("s_waitcnt lgkmcnt(0)" ::: "memory");
        __builtin_amdgcn_sched_barrier(0);
        __builtin_amdgcn_s_setprio(1);
#pragma unroll
        for (int mb = 0; mb < 2; ++mb)
#pragma unroll
            for (int nb = 0; nb < 2; ++nb)
#pragma unroll
                for (int ks = 0; ks < 2; ++ks)
                    acc[mb][nb] = __builtin_amdgcn_mfma_f32_16x16x32_bf16(aF[mb][ks], bF[nb][ks], acc[mb][nb], 0, 0, 0);
        __builtin_amdgcn_s_setprio(0);
        __builtin_amdgcn_s_barrier();

        // P2: B nb2-3 (reuse bF); stage B(t+1); end with counted drain
#pragma unroll
        for (int nb = 0; nb < 2; ++nb)
#pragma unroll
            for (int ks = 0; ks < 2; ++ks)
                bF[nb][ks] = *(const bf16x8*)(Br + (2 + nb) * 2048 + oa[ks]);
        if (t + 1 < NT) stageB(buf ^ 1, t + 1);
        __builtin_amdgcn_s_barrier();
        asm volatile("s_waitcnt lgkmcnt(0)" ::: "memory");
        __builtin_amdgcn_sched_barrier(0);
        __builtin_amdgcn_s_setprio(1);
#pragma unroll
        for (int mb = 0; mb < 2; ++mb)
#pragma unroll
            for (int nb = 0; nb < 2; ++nb)
#pragma unroll
                for (int ks = 0; ks < 2; ++ks)
                    acc[mb][2 + nb] = __builtin_amdgcn_mfma_f32_16x16x32_bf16(aF[mb][ks], bF[nb][ks], acc[mb][2 + nb], 0, 0, 0);
        __builtin_amdgcn_s_setprio(0);
        if (t + 1 < NT) asm volatile("s_waitcnt vmcnt(0)" ::: "memory");
        __builtin_amdgcn_s_barrier();
    }

#pragma unroll
    for (int mb = 0; mb < 2; ++mb) {
        int row0 = m0 + wm * 32 + mb * 16 + fq * 4;
#pragma unroll
        for (int nb = 0; nb < 4; ++nb) {
            int col = n0 + wn * 64 + nb * 16 + fr;
            float bz = bias[col];
#pragma unroll
            for (int j = 0; j < 4; ++j) {
                size_t idx = (size_t)(row0 + j) * N + col;
                float vv = acc[mb][nb][j] + bz;
                if (EPI == 0) {
                    ((unsigned short*)outp)[idx] = f2bf(vv);
                } else {
                    ((float*)outp)[idx] = vv + resid[idx];
                }
            }
        }
    }
}

// ---------------- flash attention: QBLK=128, fixed-max, zero-shuffle PV ------
__global__ __launch_bounds__(512, 4)
void attn_kernel(const unsigned short* __restrict__ QKV, const float* __restrict__ bias,
                 unsigned short* __restrict__ O) {
    __shared__ __align__(16) unsigned short lK[2][4096];
    __shared__ __align__(16) unsigned short lV[2][4096];
    const int tid = threadIdx.x, lane = tid & 63, w = tid >> 6;
    const int fr = lane & 15, fq = lane >> 4;

    const int bid = blockIdx.x;                   // 1024 blocks
    const int slice = (bid >> 5) * 8 + (bid & 7); // 0..255 = (h, q-tile)
    const int b = (bid >> 3) & 3;                 // 4 bias-sharers same XCD
    const int h = slice >> 4;
    const int q0 = (slice & 15) * 128;

    const size_t base = (size_t)b * S * QS + h * DK;
    const unsigned short* Qp = QKV + base;
    const unsigned short* Kp = QKV + base + H;
    const unsigned short* Vp = QKV + base + 2 * H;
    const size_t obase = (size_t)b * S * H + h * DK;

    bf16x8 aq[2];
    {
        const unsigned short* qp = Qp + (size_t)(q0 + w * 16 + fr) * QS + fq * 8;
        aq[0] = *(const bf16x8*)qp;
        aq[1] = *(const bf16x8*)(qp + 32);
    }

    const int chk = w * 64 + lane;
    const int rK = chk >> 3, cK = ((chk & 7) ^ (rK & 7)) * 8;
    int vk, vd;
    {
        int ch = chk;
        int dch = ch & 1, j = (ch >> 1) & 3, fqi = (ch >> 3) & 3, half = (ch >> 5) & 1,
            c = (ch >> 6) & 3, ks = (ch >> 8) & 1;
        vk = ks * 32 + half * 16 + fqi * 4 + j; vd = c * 16 + dch * 8;
    }

    f32x4 oacc[4] = {};
    float lrun = 0.f;
    const float* bias_q = bias + (size_t)h * S * S + (size_t)(q0 + w * 16 + fr) * S;

    const float SC = 0.18033688f;       // 0.125 * log2(e)
    const float BL = 1.44269504f;       // log2(e)
    const float CC = -23.08312065f;     // -16 * log2(e)

    auto stage = [&](int buf, int k0) {
        gld16(Kp + (size_t)(k0 + rK) * QS + cK, &lK[buf][w * 512]);
        gld16(Vp + (size_t)(k0 + vk) * QS + vd, &lV[buf][w * 512]);
    };

    stage(0, 0);
    int cur = 0;
    for (int kt = 0; kt < S / 64; ++kt) {
        const int k0 = kt * 64;
        __syncthreads();
        if (kt + 1 < S / 64) stage(cur ^ 1, k0 + 64);

        float4 bv4[4];
#pragma unroll
        for (int c = 0; c < 4; ++c)
            bv4[c] = *(const float4*)(bias_q + k0 + c * 16 + fq * 4);

        f32x4 sacc[4] = {};
        __builtin_amdgcn_s_setprio(1);
#pragma unroll
        for (int c = 0; c < 4; ++c) {
            int row = c * 16 + fr;
#pragma unroll
            for (int dh = 0; dh < 2; ++dh) {
                bf16x8 bk = *(const bf16x8*)((char*)lK[cur] +
                    ((row * 128 + dh * 64 + fq * 16) ^ ((row & 7) << 4)));
                sacc[c] = __builtin_amdgcn_mfma_f32_16x16x32_bf16(bk, aq[dh], sacc[c], 0, 0, 0);
            }
        }
        __builtin_amdgcn_s_setprio(0);

        float p[4][4];
#pragma unroll
        for (int c = 0; c < 4; ++c) {
            float b0 = fmaf(bv4[c].x, BL, CC);
            float b1 = fmaf(bv4[c].y, BL, CC);
            float b2 = fmaf(bv4[c].z, BL, CC);
            float b3 = fmaf(bv4[c].w, BL, CC);
            p[c][0] = exp2f(fmaf(sacc[c][0], SC, b0));
            p[c][1] = exp2f(fmaf(sacc[c][1], SC, b1));
            p[c][2] = exp2f(fmaf(sacc[c][2], SC, b2));
            p[c][3] = exp2f(fmaf(sacc[c][3], SC, b3));
            lrun += p[c][0] + p[c][1] + p[c][2] + p[c][3];
        }

        union { unsigned u[4]; bf16x8 v; } pa0, pa1;
        pa0.u[0] = pack_bf2(p[0][0], p[0][1]);
        pa0.u[1] = pack_bf2(p[0][2], p[0][3]);
        pa0.u[2] = pack_bf2(p[1][0], p[1][1]);
        pa0.u[3] = pack_bf2(p[1][2], p[1][3]);
        pa1.u[0] = pack_bf2(p[2][0], p[2][1]);
        pa1.u[1] = pack_bf2(p[2][2], p[2][3]);
        pa1.u[2] = pack_bf2(p[3][0], p[3][1]);
        pa1.u[3] = pack_bf2(p[3][2], p[3][3]);

        u16x4 ra0[4], rb0[4], ra1[4], rb1[4];
        {
            const char* v0 = (const char*)lV[cur];
            const char* v1 = (const char*)lV[cur] + 4096;
#pragma unroll
            for (int c = 0; c < 4; ++c) {
                unsigned ad = (unsigned)(unsigned long long)(v0 + c * 1024) + lane * 8;
                asm volatile("ds_read_b64_tr_b16 %0, %1" : "=&v"(ra0[c]) : "v"(ad));
                asm volatile("ds_read_b64_tr_b16 %0, %1 offset:512" : "=&v"(rb0[c]) : "v"(ad));
            }
#pragma unroll
            for (int c = 0; c < 4; ++c) {
                unsigned ad = (unsigned)(unsigned long long)(v1 + c * 1024) + lane * 8;
                asm volatile("ds_read_b64_tr_b16 %0, %1" : "=&v"(ra1[c]) : "v"(ad));
                asm volatile("ds_read_b64_tr_b16 %0, %1 offset:512" : "=&v"(rb1[c]) : "v"(ad));
            }
        }
        asm volatile("s_waitcnt lgkmcnt(8)" ::: "memory");
        __builtin_amdgcn_sched_barrier(0);
        __builtin_amdgcn_s_setprio(1);
#pragma unroll
        for (int c = 0; c < 4; ++c) {
            union { u16x4 h2[2]; bf16x8 v8; } u;
            u.h2[0] = ra0[c]; u.h2[1] = rb0[c];
            oacc[c] = __builtin_amdgcn_mfma_f32_16x16x32_bf16(pa0.v, u.v8, oacc[c], 0, 0, 0);
        }
        __builtin_amdgcn_s_setprio(0);
        asm volatile("s_waitcnt lgkmcnt(0)" ::: "memory");
        __builtin_amdgcn_sched_barrier(0);
        __builtin_amdgcn_s_setprio(1);
#pragma unroll
        for (int c = 0; c < 4; ++c) {
            union { u16x4 h2[2]; bf16x8 v8; } u;
            u.h2[0] = ra1[c]; u.h2[1] = rb1[c];
            oacc[c] = __builtin_amdgcn_mfma_f32_16x16x32_bf16(pa1.v, u.v8, oacc[c], 0, 0, 0);
        }
        __builtin_amdgcn_s_setprio(0);
        cur ^= 1;
    }

    lrun += __shfl_xor(lrun, 16);
    lrun += __shfl_xor(lrun, 32);
    float linv = 1.f / lrun;
    float lo[4];
#pragma unroll
    for (int j = 0; j < 4; ++j) lo[j] = __shfl(linv, fq * 4 + j);
#pragma unroll
    for (int c = 0; c < 4; ++c)
#pragma unroll
        for (int j = 0; j < 4; ++j) {
            int row = q0 + w * 16 + fq * 4 + j;
            int d = c * 16 + fr;
            O[obase + (size_t)row * H + d] = f2bf(oacc[c][j] * lo[j]);
        }
}

extern "C" void kernel_launch(void* const* d_in, const int* in_sizes, int n_in,
                              void* d_out, int out_size, void* d_ws, size_t ws_size,
                              hipStream_t stream) {
    const float* x    = (const float*)d_in[0];
    const float* ab   = (const float*)d_in[1];
    const float* ln1g = (const float*)d_in[2];
    const float* ln1b = (const float*)d_in[3];
    const float* Wq   = (const float*)d_in[4];
    const float* bq   = (const float*)d_in[5];
    const float* Wk   = (const float*)d_in[6];
    const float* bk   = (const float*)d_in[7];
    const float* Wv   = (const float*)d_in[8];
    const float* bv   = (const float*)d_in[9];
    const float* Wo   = (const float*)d_in[10];
    const float* bo   = (const float*)d_in[11];
    const float* ln2g = (const float*)d_in[12];
    const float* ln2b = (const float*)d_in[13];
    const float* W1   = (const float*)d_in[14];
    const float* b1   = (const float*)d_in[15];
    const float* W2   = (const float*)d_in[16];
    const float* b2   = (const float*)d_in[17];

    char* ws = (char*)d_ws;
    size_t off = 0;
    auto alloc = [&](size_t bytes) -> void* {
        void* p = ws + off;
        off += (bytes + 255) & ~(size_t)255;
        return p;
    };
    unsigned short* Wqt = (unsigned short*)alloc((size_t)H * H * 2); // q,k,v contiguous
    unsigned short* Wkt = (unsigned short*)alloc((size_t)H * H * 2);
    unsigned short* Wvt = (unsigned short*)alloc((size_t)H * H * 2);
    unsigned short* Wot = (unsigned short*)alloc((size_t)H * H * 2);
    unsigned short* W1t = (unsigned short*)alloc((size_t)H * FF * 2);
    unsigned short* W2t = (unsigned short*)alloc((size_t)H * FF * 2);
    float* bqkv        = (float*)alloc((size_t)QS * 4);
    unsigned short* ybuf = (unsigned short*)alloc((size_t)Mrows * H * 2);
    unsigned short* qkvb = (unsigned short*)alloc((size_t)Mrows * QS * 2);
    unsigned short* ob = (unsigned short*)alloc((size_t)Mrows * H * 2);
    unsigned short* hb = (unsigned short*)alloc((size_t)Mrows * FF * 2);
    (void)ws_size; (void)in_sizes; (void)n_in; (void)out_size;
    (void)Wkt; (void)Wvt;

    dim3 tb(32, 8, 1);
    wcvt_all<<<dim3(12288), tb, 0, stream>>>(Wq, Wk, Wv, Wo, W1, W2, Wqt, Wot, W1t, W2t);
    catbias<<<QS / 256, 256, 0, stream>>>(bq, bk, bv, bqkv);

    ln_kernel<<<Mrows, 256, 0, stream>>>(x, ln1g, ln1b, ybuf);

    // fused QKV projection: [8192,1024] @ [1024,3072]
    gemm8p128<0><<<dim3((Mrows / 128) * (QS / 256)), 512, 0, stream>>>(ybuf, Wqt, bqkv, nullptr, qkvb, QS, H);

    attn_kernel<<<dim3(Bb * NH * (S / 128)), 512, 0, stream>>>(qkvb, ab, ob);

    // Wo + residual: [8192,1024] @ [1024,1024] -> f32 d_out  (128^2, 2 blocks/CU)
    gemm128<2><<<dim3((Mrows / 128) * (H / 128)), 512, 0, stream>>>(ob, Wot, bo, x, d_out, H, H);

    ln_kernel<<<Mrows, 256, 0, stream>>>((const float*)d_out, ln2g, ln2b, ybuf);

    // FFN1: [8192,1024] @ [1024,4096] + gelu
    gemm8p<1><<<dim3((Mrows / 256) * (FF / 256)), 512, 0, stream>>>(ybuf, W1t, b1, hb, FF, H);

    // FFN2 + residual: [8192,4096] @ [4096,1024] -> f32 d_out  (128^2, 2 blocks/CU)
    gemm128<2><<<dim3((Mrows / 128) * (H / 128)), 512, 0, stream>>>(hb, W2t, b2, (const float*)d_out, d_out, H, FF);
}

// Round 14
// 537.818 us; speedup vs baseline: 1.0454x; 1.0454x over previous
//
#include <hip/hip_runtime.h>

#define DEVINL __device__ __forceinline__

typedef __bf16 bf16x8 __attribute__((ext_vector_type(8)));
typedef float f32x4 __attribute__((ext_vector_type(4)));
typedef unsigned short u16x4 __attribute__((ext_vector_type(4)));

static constexpr int Bb = 4, S = 2048, H = 1024, NH = 16, DK = 64, FF = 4096;
static constexpr int Mrows = Bb * S; // 8192
static constexpr int QS = 3 * H;    // fused QKV row stride

DEVINL unsigned short f2bf(float f) {
    union { __bf16 b; unsigned short u; } r;
    r.b = (__bf16)f;
    return r.u;
}

DEVINL unsigned pack_bf2(float a, float b) {
    union { __bf16 h[2]; unsigned u; } r;
    r.h[0] = (__bf16)a; r.h[1] = (__bf16)b;
    return r.u;
}

DEVINL void gld16(const void* g, void* l) {
    auto gp = reinterpret_cast<const __attribute__((address_space(1))) unsigned*>(
        reinterpret_cast<unsigned long long>(g));
    auto lp = reinterpret_cast<__attribute__((address_space(3))) unsigned*>(
        (unsigned)reinterpret_cast<unsigned long long>(l));
    __builtin_amdgcn_global_load_lds(gp, lp, 16, 0, 0);
}

// ---------------- merged weight convert: all 6 weights, one launch ----------
__global__ __launch_bounds__(256)
void wcvt_all(const float* __restrict__ Wq, const float* __restrict__ Wk,
              const float* __restrict__ Wv, const float* __restrict__ Wo,
              const float* __restrict__ W1, const float* __restrict__ W2,
              unsigned short* __restrict__ Wqt, unsigned short* __restrict__ Wot,
              unsigned short* __restrict__ W1t, unsigned short* __restrict__ W2t) {
    int id = blockIdx.x;
    const float* in; unsigned short* out; int K, N;
    if (id < 3072) {
        int which = id >> 10; id &= 1023;
        in = which == 0 ? Wq : (which == 1 ? Wk : Wv);
        out = Wqt + (size_t)which * H * H; K = H; N = H;
    } else if (id < 4096) { in = Wo; out = Wot; K = H; N = H; id -= 3072; }
    else if (id < 8192)   { in = W1; out = W1t; K = H; N = FF; id -= 4096; }
    else                  { in = W2; out = W2t; K = FF; N = H; id -= 8192; }
    const int nx = N / 32;
    const int n0 = (id % nx) * 32, k0 = (id / nx) * 32;

    __shared__ float t[32][33];
    int tx = threadIdx.x, ty = threadIdx.y;
#pragma unroll
    for (int i = 0; i < 32; i += 8) t[ty + i][tx] = in[(size_t)(k0 + ty + i) * N + n0 + tx];
    __syncthreads();
#pragma unroll
    for (int i = 0; i < 32; i += 8) out[(size_t)(n0 + ty + i) * K + k0 + tx] = f2bf(t[tx][ty + i]);
}

// ---------------- fuse q/k/v bias into one [3072] array ----------------
__global__ __launch_bounds__(256)
void catbias(const float* __restrict__ a, const float* __restrict__ b,
             const float* __restrict__ c, float* __restrict__ o) {
    int i = blockIdx.x * 256 + threadIdx.x;
    float v = (i < 1024) ? a[i] : (i < 2048 ? b[i - 1024] : c[i - 2048]);
    o[i] = v;
}

// ---------------- LayerNorm: f32 row -> bf16 row ----------------
__global__ __launch_bounds__(256)
void ln_kernel(const float* __restrict__ x, const float* __restrict__ g,
               const float* __restrict__ be, unsigned short* __restrict__ y) {
    int row = blockIdx.x, tid = threadIdx.x;
    const float4 v = ((const float4*)(x + (size_t)row * H))[tid];
    float s = v.x + v.y + v.z + v.w;
    float ss = v.x * v.x + v.y * v.y + v.z * v.z + v.w * v.w;
#pragma unroll
    for (int m = 1; m < 64; m <<= 1) { s += __shfl_xor(s, m); ss += __shfl_xor(ss, m); }
    __shared__ float red[2][4];
    int lane = tid & 63, w = tid >> 6;
    if (lane == 0) { red[0][w] = s; red[1][w] = ss; }
    __syncthreads();
    s = red[0][0] + red[0][1] + red[0][2] + red[0][3];
    ss = red[1][0] + red[1][1] + red[1][2] + red[1][3];
    float mean = s * (1.f / H);
    float var = ss * (1.f / H) - mean * mean;
    float rstd = rsqrtf(var + 1e-5f);
    float4 gv = ((const float4*)g)[tid];
    float4 bv = ((const float4*)be)[tid];
    ushort4 o;
    o.x = f2bf((v.x - mean) * rstd * gv.x + bv.x);
    o.y = f2bf((v.y - mean) * rstd * gv.y + bv.y);
    o.z = f2bf((v.z - mean) * rstd * gv.z + bv.z);
    o.w = f2bf((v.w - mean) * rstd * gv.w + bv.w);
    ((ushort4*)(y + (size_t)row * H))[tid] = o;
}

// ---------------- 256x256 8-phase GEMM (T2+T3+T4+T5), quadrant schedule ------
// EPI: 0 = store bf16, 1 = gelu->bf16
template <int EPI>
__global__ __launch_bounds__(512, 2)
void gemm8p(const unsigned short* __restrict__ A, const unsigned short* __restrict__ Bt,
            const float* __restrict__ bias, void* __restrict__ outp, int N, int K) {
    __shared__ __align__(16) char lds[131072];
    const int tid = threadIdx.x, lane = tid & 63, w = tid >> 6;
    const int wm = w >> 2, wn = w & 3;
    const int fr = lane & 15, fq = lane >> 4;
    const int nwg = gridDim.x, id = blockIdx.x;
    const int swz = (id & 7) * (nwg >> 3) + (id >> 3);
    const int m0 = (swz & 31) * 256, n0 = (swz >> 5) * 256;

    int srow[2], scol[2];
#pragma unroll
    for (int l = 0; l < 2; ++l) {
        int idx = l * 512 + tid;
        srow[l] = idx >> 3;
        scol[l] = ((idx & 7) ^ (srow[l] & 7)) * 8;
    }
    const int NT = K >> 6;

    auto stage = [&](int ht, int buf, int kt) {
        const unsigned short* src = (ht < 2) ? A : Bt;
        const int hh = ht & 1;
        char* dst = lds + ((ht < 2 ? 0 : 65536) + (buf * 2 + hh) * 16384);
        const int rbase = ((ht < 2) ? m0 : n0) + hh * 128;
        const int kb = kt * 64;
#pragma unroll
        for (int l = 0; l < 2; ++l)
            gld16(src + (size_t)(rbase + srow[l]) * K + kb + scol[l],
                  dst + (size_t)(l * 512 + tid) * 16);
    };

    int oa[2];
#pragma unroll
    for (int ks = 0; ks < 2; ++ks)
        oa[ks] = fr * 128 + (((ks * 4 + fq) ^ (fr & 7)) & 7) * 16;
    const int aBase0 = wm * 16384;
    const int bBase0 = 65536 + (wn >> 1) * 16384 + (wn & 1) * 8192;

    f32x4 acc[8][4] = {};
    bf16x8 aF[4][2], bF[4][2];

    stage(0, 0, 0); stage(1, 0, 0); stage(2, 0, 0); stage(3, 0, 0);
    if (NT > 1) {
        stage(0, 1, 1);
        asm volatile("s_waitcnt vmcnt(2)" ::: "memory");
    } else {
        asm volatile("s_waitcnt vmcnt(0)" ::: "memory");
    }
    __builtin_amdgcn_s_barrier();

    int buf = 0;
    for (int t = 0; t < NT; ++t, buf ^= 1) {
        const char* Ar = lds + aBase0 + buf * 32768;
        const char* Br = lds + bBase0 + buf * 32768;

#pragma unroll
        for (int mb = 0; mb < 4; ++mb)
#pragma unroll
            for (int ks = 0; ks < 2; ++ks)
                aF[mb][ks] = *(const bf16x8*)(Ar + mb * 2048 + oa[ks]);
#pragma unroll
        for (int nb = 0; nb < 2; ++nb)
#pragma unroll
            for (int ks = 0; ks < 2; ++ks)
                bF[nb][ks] = *(const bf16x8*)(Br + nb * 2048 + oa[ks]);
        if (t + 1 < NT) stage(1, buf ^ 1, t + 1);
        __builtin_amdgcn_s_barrier();
        asm volatile("s_waitcnt lgkmcnt(0)" ::: "memory");
        __builtin_amdgcn_sched_barrier(0);
        __builtin_amdgcn_s_setprio(1);
#pragma unroll
        for (int mb = 0; mb < 4; ++mb)
#pragma unroll
            for (int nb = 0; nb < 2; ++nb)
#pragma unroll
                for (int ks = 0; ks < 2; ++ks)
                    acc[mb][nb] = __builtin_amdgcn_mfma_f32_16x16x32_bf16(aF[mb][ks], bF[nb][ks], acc[mb][nb], 0, 0, 0);
        __builtin_amdgcn_s_setprio(0);
        __builtin_amdgcn_s_barrier();

#pragma unroll
        for (int nb = 2; nb < 4; ++nb)
#pragma unroll
            for (int ks = 0; ks < 2; ++ks)
                bF[nb][ks] = *(const bf16x8*)(Br + nb * 2048 + oa[ks]);
        if (t + 1 < NT) stage(2, buf ^ 1, t + 1);
        __builtin_amdgcn_s_barrier();
        asm volatile("s_waitcnt lgkmcnt(0)" ::: "memory");
        __builtin_amdgcn_sched_barrier(0);
        __builtin_amdgcn_s_setprio(1);
#pragma unroll
        for (int mb = 0; mb < 4; ++mb)
#pragma unroll
            for (int nb = 2; nb < 4; ++nb)
#pragma unroll
                for (int ks = 0; ks < 2; ++ks)
                    acc[mb][nb] = __builtin_amdgcn_mfma_f32_16x16x32_bf16(aF[mb][ks], bF[nb][ks], acc[mb][nb], 0, 0, 0);
        __builtin_amdgcn_s_setprio(0);
        __builtin_amdgcn_s_barrier();

#pragma unroll
        for (int mb = 0; mb < 4; ++mb)
#pragma unroll
            for (int ks = 0; ks < 2; ++ks)
                aF[mb][ks] = *(const bf16x8*)(Ar + 8192 + mb * 2048 + oa[ks]);
        if (t + 1 < NT) stage(3, buf ^ 1, t + 1);
        __builtin_amdgcn_s_barrier();
        asm volatile("s_waitcnt lgkmcnt(0)" ::: "memory");
        __builtin_amdgcn_sched_barrier(0);
        __builtin_amdgcn_s_setprio(1);
#pragma unroll
        for (int mb = 0; mb < 4; ++mb)
#pragma unroll
            for (int nb = 0; nb < 2; ++nb)
#pragma unroll
                for (int ks = 0; ks < 2; ++ks)
                    acc[4 + mb][nb] = __builtin_amdgcn_mfma_f32_16x16x32_bf16(aF[mb][ks], bF[nb][ks], acc[4 + mb][nb], 0, 0, 0);
        __builtin_amdgcn_s_setprio(0);
        __builtin_amdgcn_s_barrier();

        if (t + 2 < NT) {
            stage(0, buf, t + 2);
            asm volatile("s_waitcnt vmcnt(2)" ::: "memory");
        } else if (t + 1 < NT) {
            asm volatile("s_waitcnt vmcnt(0)" ::: "memory");
        }
        __builtin_amdgcn_s_barrier();
        __builtin_amdgcn_s_setprio(1);
#pragma unroll
        for (int mb = 0; mb < 4; ++mb)
#pragma unroll
            for (int nb = 2; nb < 4; ++nb)
#pragma unroll
                for (int ks = 0; ks < 2; ++ks)
                    acc[4 + mb][nb] = __builtin_amdgcn_mfma_f32_16x16x32_bf16(aF[mb][ks], bF[nb][ks], acc[4 + mb][nb], 0, 0, 0);
        __builtin_amdgcn_s_setprio(0);
        __builtin_amdgcn_s_barrier();
    }

#pragma unroll
    for (int mb = 0; mb < 8; ++mb) {
        int row0 = m0 + wm * 128 + mb * 16 + fq * 4;
#pragma unroll
        for (int nb = 0; nb < 4; ++nb) {
            int col = n0 + wn * 64 + nb * 16 + fr;
            float bz = bias[col];
#pragma unroll
            for (int j = 0; j < 4; ++j) {
                float vv = acc[mb][nb][j] + bz;
                size_t idx = (size_t)(row0 + j) * N + col;
                if (EPI == 0) {
                    ((unsigned short*)outp)[idx] = f2bf(vv);
                } else {
                    float tg = 0.5f * vv * (1.f + erff(vv * 0.70710678118654752f));
                    ((unsigned short*)outp)[idx] = f2bf(tg);
                }
            }
        }
    }
}

// ---------------- 128x256 8-phase GEMM -----------------
// EPI: 0 = bf16 + bias; 2 = f32 + bias + resid
template <int EPI>
__global__ __launch_bounds__(512, 2)
void gemm8p128(const unsigned short* __restrict__ A, const unsigned short* __restrict__ Bt,
               const float* __restrict__ bias, const float* __restrict__ resid,
               void* __restrict__ outp, int N, int K) {
    __shared__ __align__(16) char lds[98304];
    const int tid = threadIdx.x, lane = tid & 63, w = tid >> 6;
    const int wm = w >> 2, wn = w & 3;
    const int fr = lane & 15, fq = lane >> 4;
    const int nwg = gridDim.x, id = blockIdx.x;
    const int swz = (id & 7) * (nwg >> 3) + (id >> 3);
    const int m0 = (swz & 63) * 128, n0 = (swz >> 6) * 256;

    int srow[2], scol[2];
#pragma unroll
    for (int l = 0; l < 2; ++l) {
        int idx = l * 512 + tid;
        srow[l] = idx >> 3;
        scol[l] = ((idx & 7) ^ (srow[l] & 7)) * 8;
    }
    const int NT = K >> 6;

    auto stageA = [&](int buf, int kt) {
        char* dst = lds + buf * 16384;
#pragma unroll
        for (int l = 0; l < 2; ++l)
            gld16(A + (size_t)(m0 + srow[l]) * K + kt * 64 + scol[l],
                  dst + (size_t)(l * 512 + tid) * 16);
    };
    auto stageB = [&](int hh, int buf, int kt) {
        char* dst = lds + 32768 + buf * 32768 + hh * 16384;
#pragma unroll
        for (int l = 0; l < 2; ++l)
            gld16(Bt + (size_t)(n0 + hh * 128 + srow[l]) * K + kt * 64 + scol[l],
                  dst + (size_t)(l * 512 + tid) * 16);
    };

    int oa[2];
#pragma unroll
    for (int ks = 0; ks < 2; ++ks)
        oa[ks] = fr * 128 + (((ks * 4 + fq) ^ (fr & 7)) & 7) * 16;
    const int aWB = wm * 8192;
    const int bWB = (wn >> 1) * 16384 + (wn & 1) * 8192;

    f32x4 acc[4][4] = {};
    bf16x8 aF[2][2], bF[4][2];

    stageA(0, 0); stageB(0, 0, 0); stageB(1, 0, 0);
    if (NT > 1) {
        stageA(1, 1);
        asm volatile("s_waitcnt vmcnt(2)" ::: "memory");
    } else {
        asm volatile("s_waitcnt vmcnt(0)" ::: "memory");
    }
    __builtin_amdgcn_s_barrier();

    int buf = 0;
    for (int t = 0; t < NT; ++t, buf ^= 1) {
        const char* Ar = lds + buf * 16384 + aWB;
        const char* Br = lds + 32768 + buf * 32768 + bWB;

#pragma unroll
        for (int mb = 0; mb < 2; ++mb)
#pragma unroll
            for (int ks = 0; ks < 2; ++ks)
                aF[mb][ks] = *(const bf16x8*)(Ar + mb * 2048 + oa[ks]);
#pragma unroll
        for (int nb = 0; nb < 2; ++nb)
#pragma unroll
            for (int ks = 0; ks < 2; ++ks)
                bF[nb][ks] = *(const bf16x8*)(Br + nb * 2048 + oa[ks]);
        if (t + 1 < NT) stageB(0, buf ^ 1, t + 1);
        __builtin_amdgcn_s_barrier();
        asm volatile("s_waitcnt lgkmcnt(0)" ::: "memory");
        __builtin_amdgcn_sched_barrier(0);
        __builtin_amdgcn_s_setprio(1);
#pragma unroll
        for (int mb = 0; mb < 2; ++mb)
#pragma unroll
            for (int nb = 0; nb < 2; ++nb)
#pragma unroll
                for (int ks = 0; ks < 2; ++ks)
                    acc[mb][nb] = __builtin_amdgcn_mfma_f32_16x16x32_bf16(aF[mb][ks], bF[nb][ks], acc[mb][nb], 0, 0, 0);
        __builtin_amdgcn_s_setprio(0);
        __builtin_amdgcn_s_barrier();

#pragma unroll
        for (int nb = 2; nb < 4; ++nb)
#pragma unroll
            for (int ks = 0; ks < 2; ++ks)
                bF[nb][ks] = *(const bf16x8*)(Br + nb * 2048 + oa[ks]);
        if (t + 1 < NT) stageB(1, buf ^ 1, t + 1);
        __builtin_amdgcn_s_barrier();
        asm volatile("s_waitcnt lgkmcnt(0)" ::: "memory");
        __builtin_amdgcn_sched_barrier(0);
        __builtin_amdgcn_s_setprio(1);
#pragma unroll
        for (int mb = 0; mb < 2; ++mb)
#pragma unroll
            for (int nb = 2; nb < 4; ++nb)
#pragma unroll
                for (int ks = 0; ks < 2; ++ks)
                    acc[mb][nb] = __builtin_amdgcn_mfma_f32_16x16x32_bf16(aF[mb][ks], bF[nb][ks], acc[mb][nb], 0, 0, 0);
        __builtin_amdgcn_s_setprio(0);
        __builtin_amdgcn_s_barrier();

#pragma unroll
        for (int mb = 0; mb < 2; ++mb)
#pragma unroll
            for (int ks = 0; ks < 2; ++ks)
                aF[mb][ks] = *(const bf16x8*)(Ar + 4096 + mb * 2048 + oa[ks]);
        __builtin_amdgcn_s_barrier();
        asm volatile("s_waitcnt lgkmcnt(0)" ::: "memory");
        __builtin_amdgcn_sched_barrier(0);
        __builtin_amdgcn_s_setprio(1);
#pragma unroll
        for (int mb = 0; mb < 2; ++mb)
#pragma unroll
            for (int nb = 0; nb < 2; ++nb)
#pragma unroll
                for (int ks = 0; ks < 2; ++ks)
                    acc[2 + mb][nb] = __builtin_amdgcn_mfma_f32_16x16x32_bf16(aF[mb][ks], bF[nb][ks], acc[2 + mb][nb], 0, 0, 0);
        __builtin_amdgcn_s_setprio(0);
        __builtin_amdgcn_s_barrier();

        if (t + 2 < NT) {
            stageA(buf, t + 2);
            asm volatile("s_waitcnt vmcnt(2)" ::: "memory");
        } else if (t + 1 < NT) {
            asm volatile("s_waitcnt vmcnt(0)" ::: "memory");
        }
        __builtin_amdgcn_s_barrier();
        __builtin_amdgcn_s_setprio(1);
#pragma unroll
        for (int mb = 0; mb < 2; ++mb)
#pragma unroll
            for (int nb = 2; nb < 4; ++nb)
#pragma unroll
                for (int ks = 0; ks < 2; ++ks)
                    acc[2 + mb][nb] = __builtin_amdgcn_mfma_f32_16x16x32_bf16(aF[mb][ks], bF[nb][ks], acc[2 + mb][nb], 0, 0, 0);
        __builtin_amdgcn_s_setprio(0);
        __builtin_amdgcn_s_barrier();
    }

#pragma unroll
    for (int mb = 0; mb < 4; ++mb) {
        int row0 = m0 + wm * 64 + mb * 16 + fq * 4;
#pragma unroll
        for (int nb = 0; nb < 4; ++nb) {
            int col = n0 + wn * 64 + nb * 16 + fr;
            float bz = bias[col];
#pragma unroll
            for (int j = 0; j < 4; ++j) {
                size_t idx = (size_t)(row0 + j) * N + col;
                float vv = acc[mb][nb][j] + bz;
                if (EPI == 0) {
                    ((unsigned short*)outp)[idx] = f2bf(vv);
                } else {
                    ((float*)outp)[idx] = vv + resid[idx];
                }
            }
        }
    }
}

// ---------------- flash attention: QBLK=128, fixed-max, zero-shuffle PV ------
// P packed natively; compensating k-permutation folded into V staging coords.
// (512,4): best measured config (r9, 217 us).
__global__ __launch_bounds__(512, 4)
void attn_kernel(const unsigned short* __restrict__ QKV, const float* __restrict__ bias,
                 unsigned short* __restrict__ O) {
    __shared__ __align__(16) unsigned short lK[2][4096];
    __shared__ __align__(16) unsigned short lV[2][4096];
    const int tid = threadIdx.x, lane = tid & 63, w = tid >> 6;
    const int fr = lane & 15, fq = lane >> 4;

    const int bid = blockIdx.x;                   // 1024 blocks
    const int slice = (bid >> 5) * 8 + (bid & 7); // 0..255 = (h, q-tile)
    const int b = (bid >> 3) & 3;                 // 4 bias-sharers same XCD
    const int h = slice >> 4;
    const int q0 = (slice & 15) * 128;

    const size_t base = (size_t)b * S * QS + h * DK;
    const unsigned short* Qp = QKV + base;
    const unsigned short* Kp = QKV + base + H;
    const unsigned short* Vp = QKV + base + 2 * H;
    const size_t obase = (size_t)b * S * H + h * DK;

    bf16x8 aq[2];
    {
        const unsigned short* qp = Qp + (size_t)(q0 + w * 16 + fr) * QS + fq * 8;
        aq[0] = *(const bf16x8*)qp;
        aq[1] = *(const bf16x8*)(qp + 32);
    }

    const int chk = w * 64 + lane;
    const int rK = chk >> 3, cK = ((chk & 7) ^ (rK & 7)) * 8;
    int vk, vd;
    {
        int ch = chk;
        int dch = ch & 1, j = (ch >> 1) & 3, fqi = (ch >> 3) & 3, half = (ch >> 5) & 1,
            c = (ch >> 6) & 3, ks = (ch >> 8) & 1;
        vk = ks * 32 + half * 16 + fqi * 4 + j; vd = c * 16 + dch * 8;
    }

    f32x4 oacc[4] = {};
    float lrun = 0.f;
    const float* bias_q = bias + (size_t)h * S * S + (size_t)(q0 + w * 16 + fr) * S;

    const float SC = 0.18033688f;       // 0.125 * log2(e)
    const float BL = 1.44269504f;       // log2(e)
    const float CC = -23.08312065f;     // -16 * log2(e)

    auto stage = [&](int buf, int k0) {
        gld16(Kp + (size_t)(k0 + rK) * QS + cK, &lK[buf][w * 512]);
        gld16(Vp + (size_t)(k0 + vk) * QS + vd, &lV[buf][w * 512]);
    };

    stage(0, 0);
    int cur = 0;
    for (int kt = 0; kt < S / 64; ++kt) {
        const int k0 = kt * 64;
        __syncthreads();
        if (kt + 1 < S / 64) stage(cur ^ 1, k0 + 64);

        float4 bv4[4];
#pragma unroll
        for (int c = 0; c < 4; ++c)
            bv4[c] = *(const float4*)(bias_q + k0 + c * 16 + fq * 4);

        f32x4 sacc[4] = {};
        __builtin_amdgcn_s_setprio(1);
#pragma unroll
        for (int c = 0; c < 4; ++c) {
            int row = c * 16 + fr;
#pragma unroll
            for (int dh = 0; dh < 2; ++dh) {
                bf16x8 bk = *(const bf16x8*)((char*)lK[cur] +
                    ((row * 128 + dh * 64 + fq * 16) ^ ((row & 7) << 4)));
                sacc[c] = __builtin_amdgcn_mfma_f32_16x16x32_bf16(bk, aq[dh], sacc[c], 0, 0, 0);
            }
        }
        __builtin_amdgcn_s_setprio(0);

        float p[4][4];
#pragma unroll
        for (int c = 0; c < 4; ++c) {
            float b0 = fmaf(bv4[c].x, BL, CC);
            float b1 = fmaf(bv4[c].y, BL, CC);
            float b2 = fmaf(bv4[c].z, BL, CC);
            float b3 = fmaf(bv4[c].w, BL, CC);
            p[c][0] = exp2f(fmaf(sacc[c][0], SC, b0));
            p[c][1] = exp2f(fmaf(sacc[c][1], SC, b1));
            p[c][2] = exp2f(fmaf(sacc[c][2], SC, b2));
            p[c][3] = exp2f(fmaf(sacc[c][3], SC, b3));
            lrun += p[c][0] + p[c][1] + p[c][2] + p[c][3];
        }

        // O += P V : native P packing, zero shuffles
#pragma unroll
        for (int ks = 0; ks < 2; ++ks) {
            union { unsigned u[4]; bf16x8 v; } pa;
            pa.u[0] = pack_bf2(p[2 * ks][0], p[2 * ks][1]);
            pa.u[1] = pack_bf2(p[2 * ks][2], p[2 * ks][3]);
            pa.u[2] = pack_bf2(p[2 * ks + 1][0], p[2 * ks + 1][1]);
            pa.u[3] = pack_bf2(p[2 * ks + 1][2], p[2 * ks + 1][3]);

            const char* vb8 = (const char*)lV[cur] + ks * 4096;
            u16x4 ra[4], rb[4];
#pragma unroll
            for (int c = 0; c < 4; ++c) {
                unsigned ad = (unsigned)(unsigned long long)(vb8 + c * 1024) + lane * 8;
                asm volatile("ds_read_b64_tr_b16 %0, %1" : "=&v"(ra[c]) : "v"(ad));
                asm volatile("ds_read_b64_tr_b16 %0, %1 offset:512" : "=&v"(rb[c]) : "v"(ad));
            }
            asm volatile("s_waitcnt lgkmcnt(0)" ::: "memory");
            __builtin_amdgcn_sched_barrier(0);
            __builtin_amdgcn_s_setprio(1);
#pragma unroll
            for (int c = 0; c < 4; ++c) {
                union { u16x4 h2[2]; bf16x8 v8; } u;
                u.h2[0] = ra[c]; u.h2[1] = rb[c];
                oacc[c] = __builtin_amdgcn_mfma_f32_16x16x32_bf16(pa.v, u.v8, oacc[c], 0, 0, 0);
            }
            __builtin_amdgcn_s_setprio(0);
        }
        cur ^= 1;
    }

    lrun += __shfl_xor(lrun, 16);
    lrun += __shfl_xor(lrun, 32);
    float linv = 1.f / lrun;
    float lo[4];
#pragma unroll
    for (int j = 0; j < 4; ++j) lo[j] = __shfl(linv, fq * 4 + j);
#pragma unroll
    for (int c = 0; c < 4; ++c)
#pragma unroll
        for (int j = 0; j < 4; ++j) {
            int row = q0 + w * 16 + fq * 4 + j;
            int d = c * 16 + fr;
            O[obase + (size_t)row * H + d] = f2bf(oacc[c][j] * lo[j]);
        }
}

extern "C" void kernel_launch(void* const* d_in, const int* in_sizes, int n_in,
                              void* d_out, int out_size, void* d_ws, size_t ws_size,
                              hipStream_t stream) {
    const float* x    = (const float*)d_in[0];
    const float* ab   = (const float*)d_in[1];
    const float* ln1g = (const float*)d_in[2];
    const float* ln1b = (const float*)d_in[3];
    const float* Wq   = (const float*)d_in[4];
    const float* bq   = (const float*)d_in[5];
    const float* Wk   = (const float*)d_in[6];
    const float* bk   = (const float*)d_in[7];
    const float* Wv   = (const float*)d_in[8];
    const float* bv   = (const float*)d_in[9];
    const float* Wo   = (const float*)d_in[10];
    const float* bo   = (const float*)d_in[11];
    const float* ln2g = (const float*)d_in[12];
    const float* ln2b = (const float*)d_in[13];
    const float* W1   = (const float*)d_in[14];
    const float* b1   = (const float*)d_in[15];
    const float* W2   = (const float*)d_in[16];
    const float* b2   = (const float*)d_in[17];

    char* ws = (char*)d_ws;
    size_t off = 0;
    auto alloc = [&](size_t bytes) -> void* {
        void* p = ws + off;
        off += (bytes + 255) & ~(size_t)255;
        return p;
    };
    unsigned short* Wqt = (unsigned short*)alloc((size_t)H * H * 2); // q,k,v contiguous
    unsigned short* Wkt = (unsigned short*)alloc((size_t)H * H * 2);
    unsigned short* Wvt = (unsigned short*)alloc((size_t)H * H * 2);
    unsigned short* Wot = (unsigned short*)alloc((size_t)H * H * 2);
    unsigned short* W1t = (unsigned short*)alloc((size_t)H * FF * 2);
    unsigned short* W2t = (unsigned short*)alloc((size_t)H * FF * 2);
    float* bqkv        = (float*)alloc((size_t)QS * 4);
    unsigned short* ybuf = (unsigned short*)alloc((size_t)Mrows * H * 2);
    unsigned short* qkvb = (unsigned short*)alloc((size_t)Mrows * QS * 2);
    unsigned short* ob = (unsigned short*)alloc((size_t)Mrows * H * 2);
    unsigned short* hb = (unsigned short*)alloc((size_t)Mrows * FF * 2);
    (void)ws_size; (void)in_sizes; (void)n_in; (void)out_size;
    (void)Wkt; (void)Wvt;

    dim3 tb(32, 8, 1);
    wcvt_all<<<dim3(12288), tb, 0, stream>>>(Wq, Wk, Wv, Wo, W1, W2, Wqt, Wot, W1t, W2t);
    catbias<<<QS / 256, 256, 0, stream>>>(bq, bk, bv, bqkv);

    ln_kernel<<<Mrows, 256, 0, stream>>>(x, ln1g, ln1b, ybuf);

    // fused QKV projection: [8192,1024] @ [1024,3072]
    gemm8p128<0><<<dim3((Mrows / 128) * (QS / 256)), 512, 0, stream>>>(ybuf, Wqt, bqkv, nullptr, qkvb, QS, H);

    attn_kernel<<<dim3(Bb * NH * (S / 128)), 512, 0, stream>>>(qkvb, ab, ob);

    // Wo + residual: [8192,1024] @ [1024,1024] -> f32 d_out
    gemm8p128<2><<<dim3((Mrows / 128) * (H / 256)), 512, 0, stream>>>(ob, Wot, bo, x, d_out, H, H);

    ln_kernel<<<Mrows, 256, 0, stream>>>((const float*)d_out, ln2g, ln2b, ybuf);

    // FFN1: [8192,1024] @ [1024,4096] + gelu
    gemm8p<1><<<dim3((Mrows / 256) * (FF / 256)), 512, 0, stream>>>(ybuf, W1t, b1, hb, FF, H);

    // FFN2 + residual: [8192,4096] @ [4096,1024] -> f32 d_out
    gemm8p128<2><<<dim3((Mrows / 128) * (H / 256)), 512, 0, stream>>>(hb, W2t, b2, (const float*)d_out, d_out, H, FF);
}

// Round 15
// 516.325 us; speedup vs baseline: 1.0889x; 1.0416x over previous
//
#include <hip/hip_runtime.h>

#define DEVINL __device__ __forceinline__

typedef __bf16 bf16x8 __attribute__((ext_vector_type(8)));
typedef float f32x4 __attribute__((ext_vector_type(4)));
typedef unsigned short u16x4 __attribute__((ext_vector_type(4)));

static constexpr int Bb = 4, S = 2048, H = 1024, NH = 16, DK = 64, FF = 4096;
static constexpr int Mrows = Bb * S; // 8192
static constexpr int QS = 3 * H;    // fused QKV row stride

DEVINL unsigned short f2bf(float f) {
    union { __bf16 b; unsigned short u; } r;
    r.b = (__bf16)f;
    return r.u;
}

DEVINL unsigned pack_bf2(float a, float b) {
    union { __bf16 h[2]; unsigned u; } r;
    r.h[0] = (__bf16)a; r.h[1] = (__bf16)b;
    return r.u;
}

DEVINL void gld16(const void* g, void* l) {
    auto gp = reinterpret_cast<const __attribute__((address_space(1))) unsigned*>(
        reinterpret_cast<unsigned long long>(g));
    auto lp = reinterpret_cast<__attribute__((address_space(3))) unsigned*>(
        (unsigned)reinterpret_cast<unsigned long long>(l));
    __builtin_amdgcn_global_load_lds(gp, lp, 16, 0, 0);
}

// ---------------- merged weight convert: all 6 weights, one launch ----------
__global__ __launch_bounds__(256)
void wcvt_all(const float* __restrict__ Wq, const float* __restrict__ Wk,
              const float* __restrict__ Wv, const float* __restrict__ Wo,
              const float* __restrict__ W1, const float* __restrict__ W2,
              unsigned short* __restrict__ Wqt, unsigned short* __restrict__ Wot,
              unsigned short* __restrict__ W1t, unsigned short* __restrict__ W2t) {
    int id = blockIdx.x;
    const float* in; unsigned short* out; int K, N;
    if (id < 3072) {
        int which = id >> 10; id &= 1023;
        in = which == 0 ? Wq : (which == 1 ? Wk : Wv);
        out = Wqt + (size_t)which * H * H; K = H; N = H;
    } else if (id < 4096) { in = Wo; out = Wot; K = H; N = H; id -= 3072; }
    else if (id < 8192)   { in = W1; out = W1t; K = H; N = FF; id -= 4096; }
    else                  { in = W2; out = W2t; K = FF; N = H; id -= 8192; }
    const int nx = N / 32;
    const int n0 = (id % nx) * 32, k0 = (id / nx) * 32;

    __shared__ float t[32][33];
    int tx = threadIdx.x, ty = threadIdx.y;
#pragma unroll
    for (int i = 0; i < 32; i += 8) t[ty + i][tx] = in[(size_t)(k0 + ty + i) * N + n0 + tx];
    __syncthreads();
#pragma unroll
    for (int i = 0; i < 32; i += 8) out[(size_t)(n0 + ty + i) * K + k0 + tx] = f2bf(t[tx][ty + i]);
}

// ---------------- fuse q/k/v bias into one [3072] array ----------------
__global__ __launch_bounds__(256)
void catbias(const float* __restrict__ a, const float* __restrict__ b,
             const float* __restrict__ c, float* __restrict__ o) {
    int i = blockIdx.x * 256 + threadIdx.x;
    float v = (i < 1024) ? a[i] : (i < 2048 ? b[i - 1024] : c[i - 2048]);
    o[i] = v;
}

// ---------------- LayerNorm: f32 row -> bf16 row ----------------
__global__ __launch_bounds__(256)
void ln_kernel(const float* __restrict__ x, const float* __restrict__ g,
               const float* __restrict__ be, unsigned short* __restrict__ y) {
    int row = blockIdx.x, tid = threadIdx.x;
    const float4 v = ((const float4*)(x + (size_t)row * H))[tid];
    float s = v.x + v.y + v.z + v.w;
    float ss = v.x * v.x + v.y * v.y + v.z * v.z + v.w * v.w;
#pragma unroll
    for (int m = 1; m < 64; m <<= 1) { s += __shfl_xor(s, m); ss += __shfl_xor(ss, m); }
    __shared__ float red[2][4];
    int lane = tid & 63, w = tid >> 6;
    if (lane == 0) { red[0][w] = s; red[1][w] = ss; }
    __syncthreads();
    s = red[0][0] + red[0][1] + red[0][2] + red[0][3];
    ss = red[1][0] + red[1][1] + red[1][2] + red[1][3];
    float mean = s * (1.f / H);
    float var = ss * (1.f / H) - mean * mean;
    float rstd = rsqrtf(var + 1e-5f);
    float4 gv = ((const float4*)g)[tid];
    float4 bv = ((const float4*)be)[tid];
    ushort4 o;
    o.x = f2bf((v.x - mean) * rstd * gv.x + bv.x);
    o.y = f2bf((v.y - mean) * rstd * gv.y + bv.y);
    o.z = f2bf((v.z - mean) * rstd * gv.z + bv.z);
    o.w = f2bf((v.w - mean) * rstd * gv.w + bv.w);
    ((ushort4*)(y + (size_t)row * H))[tid] = o;
}

// ---------------- 256x256 8-phase GEMM (T2+T3+T4+T5), quadrant schedule ------
// EPI: 0 = store bf16, 1 = gelu->bf16
template <int EPI>
__global__ __launch_bounds__(512, 2)
void gemm8p(const unsigned short* __restrict__ A, const unsigned short* __restrict__ Bt,
            const float* __restrict__ bias, void* __restrict__ outp, int N, int K) {
    __shared__ __align__(16) char lds[131072];
    const int tid = threadIdx.x, lane = tid & 63, w = tid >> 6;
    const int wm = w >> 2, wn = w & 3;
    const int fr = lane & 15, fq = lane >> 4;
    const int nwg = gridDim.x, id = blockIdx.x;
    const int swz = (id & 7) * (nwg >> 3) + (id >> 3);
    const int m0 = (swz & 31) * 256, n0 = (swz >> 5) * 256;

    int srow[2], scol[2];
#pragma unroll
    for (int l = 0; l < 2; ++l) {
        int idx = l * 512 + tid;
        srow[l] = idx >> 3;
        scol[l] = ((idx & 7) ^ (srow[l] & 7)) * 8;
    }
    const int NT = K >> 6;

    auto stage = [&](int ht, int buf, int kt) {
        const unsigned short* src = (ht < 2) ? A : Bt;
        const int hh = ht & 1;
        char* dst = lds + ((ht < 2 ? 0 : 65536) + (buf * 2 + hh) * 16384);
        const int rbase = ((ht < 2) ? m0 : n0) + hh * 128;
        const int kb = kt * 64;
#pragma unroll
        for (int l = 0; l < 2; ++l)
            gld16(src + (size_t)(rbase + srow[l]) * K + kb + scol[l],
                  dst + (size_t)(l * 512 + tid) * 16);
    };

    int oa[2];
#pragma unroll
    for (int ks = 0; ks < 2; ++ks)
        oa[ks] = fr * 128 + (((ks * 4 + fq) ^ (fr & 7)) & 7) * 16;
    const int aBase0 = wm * 16384;
    const int bBase0 = 65536 + (wn >> 1) * 16384 + (wn & 1) * 8192;

    f32x4 acc[8][4] = {};
    bf16x8 aF[4][2], bF[4][2];

    stage(0, 0, 0); stage(1, 0, 0); stage(2, 0, 0); stage(3, 0, 0);
    if (NT > 1) {
        stage(0, 1, 1);
        asm volatile("s_waitcnt vmcnt(2)" ::: "memory");
    } else {
        asm volatile("s_waitcnt vmcnt(0)" ::: "memory");
    }
    __builtin_amdgcn_s_barrier();

    int buf = 0;
    for (int t = 0; t < NT; ++t, buf ^= 1) {
        const char* Ar = lds + aBase0 + buf * 32768;
        const char* Br = lds + bBase0 + buf * 32768;

#pragma unroll
        for (int mb = 0; mb < 4; ++mb)
#pragma unroll
            for (int ks = 0; ks < 2; ++ks)
                aF[mb][ks] = *(const bf16x8*)(Ar + mb * 2048 + oa[ks]);
#pragma unroll
        for (int nb = 0; nb < 2; ++nb)
#pragma unroll
            for (int ks = 0; ks < 2; ++ks)
                bF[nb][ks] = *(const bf16x8*)(Br + nb * 2048 + oa[ks]);
        if (t + 1 < NT) stage(1, buf ^ 1, t + 1);
        __builtin_amdgcn_s_barrier();
        asm volatile("s_waitcnt lgkmcnt(0)" ::: "memory");
        __builtin_amdgcn_sched_barrier(0);
        __builtin_amdgcn_s_setprio(1);
#pragma unroll
        for (int mb = 0; mb < 4; ++mb)
#pragma unroll
            for (int nb = 0; nb < 2; ++nb)
#pragma unroll
                for (int ks = 0; ks < 2; ++ks)
                    acc[mb][nb] = __builtin_amdgcn_mfma_f32_16x16x32_bf16(aF[mb][ks], bF[nb][ks], acc[mb][nb], 0, 0, 0);
        __builtin_amdgcn_s_setprio(0);
        __builtin_amdgcn_s_barrier();

#pragma unroll
        for (int nb = 2; nb < 4; ++nb)
#pragma unroll
            for (int ks = 0; ks < 2; ++ks)
                bF[nb][ks] = *(const bf16x8*)(Br + nb * 2048 + oa[ks]);
        if (t + 1 < NT) stage(2, buf ^ 1, t + 1);
        __builtin_amdgcn_s_barrier();
        asm volatile("s_waitcnt lgkmcnt(0)" ::: "memory");
        __builtin_amdgcn_sched_barrier(0);
        __builtin_amdgcn_s_setprio(1);
#pragma unroll
        for (int mb = 0; mb < 4; ++mb)
#pragma unroll
            for (int nb = 2; nb < 4; ++nb)
#pragma unroll
                for (int ks = 0; ks < 2; ++ks)
                    acc[mb][nb] = __builtin_amdgcn_mfma_f32_16x16x32_bf16(aF[mb][ks], bF[nb][ks], acc[mb][nb], 0, 0, 0);
        __builtin_amdgcn_s_setprio(0);
        __builtin_amdgcn_s_barrier();

#pragma unroll
        for (int mb = 0; mb < 4; ++mb)
#pragma unroll
            for (int ks = 0; ks < 2; ++ks)
                aF[mb][ks] = *(const bf16x8*)(Ar + 8192 + mb * 2048 + oa[ks]);
        if (t + 1 < NT) stage(3, buf ^ 1, t + 1);
        __builtin_amdgcn_s_barrier();
        asm volatile("s_waitcnt lgkmcnt(0)" ::: "memory");
        __builtin_amdgcn_sched_barrier(0);
        __builtin_amdgcn_s_setprio(1);
#pragma unroll
        for (int mb = 0; mb < 4; ++mb)
#pragma unroll
            for (int nb = 0; nb < 2; ++nb)
#pragma unroll
                for (int ks = 0; ks < 2; ++ks)
                    acc[4 + mb][nb] = __builtin_amdgcn_mfma_f32_16x16x32_bf16(aF[mb][ks], bF[nb][ks], acc[4 + mb][nb], 0, 0, 0);
        __builtin_amdgcn_s_setprio(0);
        __builtin_amdgcn_s_barrier();

        if (t + 2 < NT) {
            stage(0, buf, t + 2);
            asm volatile("s_waitcnt vmcnt(2)" ::: "memory");
        } else if (t + 1 < NT) {
            asm volatile("s_waitcnt vmcnt(0)" ::: "memory");
        }
        __builtin_amdgcn_s_barrier();
        __builtin_amdgcn_s_setprio(1);
#pragma unroll
        for (int mb = 0; mb < 4; ++mb)
#pragma unroll
            for (int nb = 2; nb < 4; ++nb)
#pragma unroll
                for (int ks = 0; ks < 2; ++ks)
                    acc[4 + mb][nb] = __builtin_amdgcn_mfma_f32_16x16x32_bf16(aF[mb][ks], bF[nb][ks], acc[4 + mb][nb], 0, 0, 0);
        __builtin_amdgcn_s_setprio(0);
        __builtin_amdgcn_s_barrier();
    }

#pragma unroll
    for (int mb = 0; mb < 8; ++mb) {
        int row0 = m0 + wm * 128 + mb * 16 + fq * 4;
#pragma unroll
        for (int nb = 0; nb < 4; ++nb) {
            int col = n0 + wn * 64 + nb * 16 + fr;
            float bz = bias[col];
#pragma unroll
            for (int j = 0; j < 4; ++j) {
                float vv = acc[mb][nb][j] + bz;
                size_t idx = (size_t)(row0 + j) * N + col;
                if (EPI == 0) {
                    ((unsigned short*)outp)[idx] = f2bf(vv);
                } else {
                    float tg = 0.5f * vv * (1.f + erff(vv * 0.70710678118654752f));
                    ((unsigned short*)outp)[idx] = f2bf(tg);
                }
            }
        }
    }
}

// ---------------- 128x256 8-phase GEMM -----------------
// EPI: 0 = bf16 + bias; 2 = f32 + bias + resid
template <int EPI>
__global__ __launch_bounds__(512, 2)
void gemm8p128(const unsigned short* __restrict__ A, const unsigned short* __restrict__ Bt,
               const float* __restrict__ bias, const float* __restrict__ resid,
               void* __restrict__ outp, int N, int K) {
    __shared__ __align__(16) char lds[98304];
    const int tid = threadIdx.x, lane = tid & 63, w = tid >> 6;
    const int wm = w >> 2, wn = w & 3;
    const int fr = lane & 15, fq = lane >> 4;
    const int nwg = gridDim.x, id = blockIdx.x;
    const int swz = (id & 7) * (nwg >> 3) + (id >> 3);
    const int m0 = (swz & 63) * 128, n0 = (swz >> 6) * 256;

    int srow[2], scol[2];
#pragma unroll
    for (int l = 0; l < 2; ++l) {
        int idx = l * 512 + tid;
        srow[l] = idx >> 3;
        scol[l] = ((idx & 7) ^ (srow[l] & 7)) * 8;
    }
    const int NT = K >> 6;

    auto stageA = [&](int buf, int kt) {
        char* dst = lds + buf * 16384;
#pragma unroll
        for (int l = 0; l < 2; ++l)
            gld16(A + (size_t)(m0 + srow[l]) * K + kt * 64 + scol[l],
                  dst + (size_t)(l * 512 + tid) * 16);
    };
    auto stageB = [&](int hh, int buf, int kt) {
        char* dst = lds + 32768 + buf * 32768 + hh * 16384;
#pragma unroll
        for (int l = 0; l < 2; ++l)
            gld16(Bt + (size_t)(n0 + hh * 128 + srow[l]) * K + kt * 64 + scol[l],
                  dst + (size_t)(l * 512 + tid) * 16);
    };

    int oa[2];
#pragma unroll
    for (int ks = 0; ks < 2; ++ks)
        oa[ks] = fr * 128 + (((ks * 4 + fq) ^ (fr & 7)) & 7) * 16;
    const int aWB = wm * 8192;
    const int bWB = (wn >> 1) * 16384 + (wn & 1) * 8192;

    f32x4 acc[4][4] = {};
    bf16x8 aF[2][2], bF[4][2];

    stageA(0, 0); stageB(0, 0, 0); stageB(1, 0, 0);
    if (NT > 1) {
        stageA(1, 1);
        asm volatile("s_waitcnt vmcnt(2)" ::: "memory");
    } else {
        asm volatile("s_waitcnt vmcnt(0)" ::: "memory");
    }
    __builtin_amdgcn_s_barrier();

    int buf = 0;
    for (int t = 0; t < NT; ++t, buf ^= 1) {
        const char* Ar = lds + buf * 16384 + aWB;
        const char* Br = lds + 32768 + buf * 32768 + bWB;

#pragma unroll
        for (int mb = 0; mb < 2; ++mb)
#pragma unroll
            for (int ks = 0; ks < 2; ++ks)
                aF[mb][ks] = *(const bf16x8*)(Ar + mb * 2048 + oa[ks]);
#pragma unroll
        for (int nb = 0; nb < 2; ++nb)
#pragma unroll
            for (int ks = 0; ks < 2; ++ks)
                bF[nb][ks] = *(const bf16x8*)(Br + nb * 2048 + oa[ks]);
        if (t + 1 < NT) stageB(0, buf ^ 1, t + 1);
        __builtin_amdgcn_s_barrier();
        asm volatile("s_waitcnt lgkmcnt(0)" ::: "memory");
        __builtin_amdgcn_sched_barrier(0);
        __builtin_amdgcn_s_setprio(1);
#pragma unroll
        for (int mb = 0; mb < 2; ++mb)
#pragma unroll
            for (int nb = 0; nb < 2; ++nb)
#pragma unroll
                for (int ks = 0; ks < 2; ++ks)
                    acc[mb][nb] = __builtin_amdgcn_mfma_f32_16x16x32_bf16(aF[mb][ks], bF[nb][ks], acc[mb][nb], 0, 0, 0);
        __builtin_amdgcn_s_setprio(0);
        __builtin_amdgcn_s_barrier();

#pragma unroll
        for (int nb = 2; nb < 4; ++nb)
#pragma unroll
            for (int ks = 0; ks < 2; ++ks)
                bF[nb][ks] = *(const bf16x8*)(Br + nb * 2048 + oa[ks]);
        if (t + 1 < NT) stageB(1, buf ^ 1, t + 1);
        __builtin_amdgcn_s_barrier();
        asm volatile("s_waitcnt lgkmcnt(0)" ::: "memory");
        __builtin_amdgcn_sched_barrier(0);
        __builtin_amdgcn_s_setprio(1);
#pragma unroll
        for (int mb = 0; mb < 2; ++mb)
#pragma unroll
            for (int nb = 2; nb < 4; ++nb)
#pragma unroll
                for (int ks = 0; ks < 2; ++ks)
                    acc[mb][nb] = __builtin_amdgcn_mfma_f32_16x16x32_bf16(aF[mb][ks], bF[nb][ks], acc[mb][nb], 0, 0, 0);
        __builtin_amdgcn_s_setprio(0);
        __builtin_amdgcn_s_barrier();

#pragma unroll
        for (int mb = 0; mb < 2; ++mb)
#pragma unroll
            for (int ks = 0; ks < 2; ++ks)
                aF[mb][ks] = *(const bf16x8*)(Ar + 4096 + mb * 2048 + oa[ks]);
        __builtin_amdgcn_s_barrier();
        asm volatile("s_waitcnt lgkmcnt(0)" ::: "memory");
        __builtin_amdgcn_sched_barrier(0);
        __builtin_amdgcn_s_setprio(1);
#pragma unroll
        for (int mb = 0; mb < 2; ++mb)
#pragma unroll
            for (int nb = 0; nb < 2; ++nb)
#pragma unroll
                for (int ks = 0; ks < 2; ++ks)
                    acc[2 + mb][nb] = __builtin_amdgcn_mfma_f32_16x16x32_bf16(aF[mb][ks], bF[nb][ks], acc[2 + mb][nb], 0, 0, 0);
        __builtin_amdgcn_s_setprio(0);
        __builtin_amdgcn_s_barrier();

        if (t + 2 < NT) {
            stageA(buf, t + 2);
            asm volatile("s_waitcnt vmcnt(2)" ::: "memory");
        } else if (t + 1 < NT) {
            asm volatile("s_waitcnt vmcnt(0)" ::: "memory");
        }
        __builtin_amdgcn_s_barrier();
        __builtin_amdgcn_s_setprio(1);
#pragma unroll
        for (int mb = 0; mb < 2; ++mb)
#pragma unroll
            for (int nb = 2; nb < 4; ++nb)
#pragma unroll
                for (int ks = 0; ks < 2; ++ks)
                    acc[2 + mb][nb] = __builtin_amdgcn_mfma_f32_16x16x32_bf16(aF[mb][ks], bF[nb][ks], acc[2 + mb][nb], 0, 0, 0);
        __builtin_amdgcn_s_setprio(0);
        __builtin_amdgcn_s_barrier();
    }

#pragma unroll
    for (int mb = 0; mb < 4; ++mb) {
        int row0 = m0 + wm * 64 + mb * 16 + fq * 4;
#pragma unroll
        for (int nb = 0; nb < 4; ++nb) {
            int col = n0 + wn * 64 + nb * 16 + fr;
            float bz = bias[col];
#pragma unroll
            for (int j = 0; j < 4; ++j) {
                size_t idx = (size_t)(row0 + j) * N + col;
                float vv = acc[mb][nb][j] + bz;
                if (EPI == 0) {
                    ((unsigned short*)outp)[idx] = f2bf(vv);
                } else {
                    ((float*)outp)[idx] = vv + resid[idx];
                }
            }
        }
    }
}

// ---------------- flash attention: QBLK=128, fixed-max, zero-shuffle PV ------
// T15 1-deep pipeline: stage(kt+1) | QK(kt) | PV(kt-1, pa from prev iter) |
// softmax(kt)->pa. Fixed-max softmax => no rescale coupling, so PV(kt-1) is
// independent of softmax(kt). 3-buffer LDS rotation (stage/QK/PV).
__global__ __launch_bounds__(512, 4)
void attn_kernel(const unsigned short* __restrict__ QKV, const float* __restrict__ bias,
                 unsigned short* __restrict__ O) {
    __shared__ __align__(16) unsigned short lK[3][4096];
    __shared__ __align__(16) unsigned short lV[3][4096];
    const int tid = threadIdx.x, lane = tid & 63, w = tid >> 6;
    const int fr = lane & 15, fq = lane >> 4;

    const int bid = blockIdx.x;                   // 1024 blocks
    const int slice = (bid >> 5) * 8 + (bid & 7); // 0..255 = (h, q-tile)
    const int b = (bid >> 3) & 3;                 // 4 bias-sharers same XCD
    const int h = slice >> 4;
    const int q0 = (slice & 15) * 128;

    const size_t base = (size_t)b * S * QS + h * DK;
    const unsigned short* Qp = QKV + base;
    const unsigned short* Kp = QKV + base + H;
    const unsigned short* Vp = QKV + base + 2 * H;
    const size_t obase = (size_t)b * S * H + h * DK;

    bf16x8 aq[2];
    {
        const unsigned short* qp = Qp + (size_t)(q0 + w * 16 + fr) * QS + fq * 8;
        aq[0] = *(const bf16x8*)qp;
        aq[1] = *(const bf16x8*)(qp + 32);
    }

    const int chk = w * 64 + lane;
    const int rK = chk >> 3, cK = ((chk & 7) ^ (rK & 7)) * 8;
    int vk, vd;
    {
        int ch = chk;
        int dch = ch & 1, j = (ch >> 1) & 3, fqi = (ch >> 3) & 3, half = (ch >> 5) & 1,
            c = (ch >> 6) & 3, ks = (ch >> 8) & 1;
        vk = ks * 32 + half * 16 + fqi * 4 + j; vd = c * 16 + dch * 8;
    }

    f32x4 oacc[4] = {};
    float lrun = 0.f;
    const float* bias_q = bias + (size_t)h * S * S + (size_t)(q0 + w * 16 + fr) * S;

    const float SC = 0.18033688f;       // 0.125 * log2(e)
    const float BL = 1.44269504f;       // log2(e)
    const float CC = -23.08312065f;     // -16 * log2(e)

    auto stage = [&](int buf, int k0) {
        gld16(Kp + (size_t)(k0 + rK) * QS + cK, &lK[buf][w * 512]);
        gld16(Vp + (size_t)(k0 + vk) * QS + vd, &lV[buf][w * 512]);
    };

    union pa_t { unsigned u[4]; bf16x8 v; };
    pa_t pa0, pa1; // loop-carried packed P for the previous tile

    stage(0, 0);
    __syncthreads();       // tile0 staged
    stage(1, 64);          // tile1 in flight

    // ---- prologue: tile 0 QK + softmax (no PV yet) ----
    {
        float4 bv4[4];
#pragma unroll
        for (int c = 0; c < 4; ++c)
            bv4[c] = *(const float4*)(bias_q + c * 16 + fq * 4);
        f32x4 sacc[4] = {};
        __builtin_amdgcn_s_setprio(1);
#pragma unroll
        for (int c = 0; c < 4; ++c) {
            int row = c * 16 + fr;
#pragma unroll
            for (int dh = 0; dh < 2; ++dh) {
                bf16x8 bk = *(const bf16x8*)((char*)&lK[0][0] +
                    ((row * 128 + dh * 64 + fq * 16) ^ ((row & 7) << 4)));
                sacc[c] = __builtin_amdgcn_mfma_f32_16x16x32_bf16(bk, aq[dh], sacc[c], 0, 0, 0);
            }
        }
        __builtin_amdgcn_s_setprio(0);
        float p[4][4];
#pragma unroll
        for (int c = 0; c < 4; ++c) {
            float b0 = fmaf(bv4[c].x, BL, CC);
            float b1 = fmaf(bv4[c].y, BL, CC);
            float b2 = fmaf(bv4[c].z, BL, CC);
            float b3 = fmaf(bv4[c].w, BL, CC);
            p[c][0] = exp2f(fmaf(sacc[c][0], SC, b0));
            p[c][1] = exp2f(fmaf(sacc[c][1], SC, b1));
            p[c][2] = exp2f(fmaf(sacc[c][2], SC, b2));
            p[c][3] = exp2f(fmaf(sacc[c][3], SC, b3));
            lrun += p[c][0] + p[c][1] + p[c][2] + p[c][3];
        }
        pa0.u[0] = pack_bf2(p[0][0], p[0][1]);
        pa0.u[1] = pack_bf2(p[0][2], p[0][3]);
        pa0.u[2] = pack_bf2(p[1][0], p[1][1]);
        pa0.u[3] = pack_bf2(p[1][2], p[1][3]);
        pa1.u[0] = pack_bf2(p[2][0], p[2][1]);
        pa1.u[1] = pack_bf2(p[2][2], p[2][3]);
        pa1.u[2] = pack_bf2(p[3][0], p[3][1]);
        pa1.u[3] = pack_bf2(p[3][2], p[3][3]);
    }

    int bST = 2, bQK = 1, bPV = 0;
    for (int kt = 1; kt < S / 64; ++kt) {
        __syncthreads();   // buf[bQK] staged; prev iter's reads of buf[bST] done
        if (kt + 1 < S / 64) stage(bST, (kt + 1) * 64);

        float4 bv4[4];
#pragma unroll
        for (int c = 0; c < 4; ++c)
            bv4[c] = *(const float4*)(bias_q + kt * 64 + c * 16 + fq * 4);

        // QK for tile kt
        f32x4 sacc[4] = {};
        __builtin_amdgcn_s_setprio(1);
#pragma unroll
        for (int c = 0; c < 4; ++c) {
            int row = c * 16 + fr;
#pragma unroll
            for (int dh = 0; dh < 2; ++dh) {
                bf16x8 bk = *(const bf16x8*)((char*)&lK[bQK][0] +
                    ((row * 128 + dh * 64 + fq * 16) ^ ((row & 7) << 4)));
                sacc[c] = __builtin_amdgcn_mfma_f32_16x16x32_bf16(bk, aq[dh], sacc[c], 0, 0, 0);
            }
        }
        __builtin_amdgcn_s_setprio(0);

        // PV for tile kt-1 (pa0/pa1 from previous iteration) — independent of sacc
        {
            const char* v0 = (const char*)&lV[bPV][0];
            const char* v1 = v0 + 4096;
            u16x4 ra0[4], rb0[4], ra1[4], rb1[4];
#pragma unroll
            for (int c = 0; c < 4; ++c) {
                unsigned ad = (unsigned)(unsigned long long)(v0 + c * 1024) + lane * 8;
                asm volatile("ds_read_b64_tr_b16 %0, %1" : "=&v"(ra0[c]) : "v"(ad));
                asm volatile("ds_read_b64_tr_b16 %0, %1 offset:512" : "=&v"(rb0[c]) : "v"(ad));
            }
#pragma unroll
            for (int c = 0; c < 4; ++c) {
                unsigned ad = (unsigned)(unsigned long long)(v1 + c * 1024) + lane * 8;
                asm volatile("ds_read_b64_tr_b16 %0, %1" : "=&v"(ra1[c]) : "v"(ad));
                asm volatile("ds_read_b64_tr_b16 %0, %1 offset:512" : "=&v"(rb1[c]) : "v"(ad));
            }
            asm volatile("s_waitcnt lgkmcnt(0)" ::: "memory");
            __builtin_amdgcn_sched_barrier(0);
            __builtin_amdgcn_s_setprio(1);
#pragma unroll
            for (int c = 0; c < 4; ++c) {
                union { u16x4 h2[2]; bf16x8 v8; } u;
                u.h2[0] = ra0[c]; u.h2[1] = rb0[c];
                oacc[c] = __builtin_amdgcn_mfma_f32_16x16x32_bf16(pa0.v, u.v8, oacc[c], 0, 0, 0);
            }
#pragma unroll
            for (int c = 0; c < 4; ++c) {
                union { u16x4 h2[2]; bf16x8 v8; } u;
                u.h2[0] = ra1[c]; u.h2[1] = rb1[c];
                oacc[c] = __builtin_amdgcn_mfma_f32_16x16x32_bf16(pa1.v, u.v8, oacc[c], 0, 0, 0);
            }
            __builtin_amdgcn_s_setprio(0);
            __builtin_amdgcn_sched_barrier(0);
        }

        // softmax for tile kt -> pa0/pa1 (overlaps PV MFMA drain)
        {
            float p[4][4];
#pragma unroll
            for (int c = 0; c < 4; ++c) {
                float b0 = fmaf(bv4[c].x, BL, CC);
                float b1 = fmaf(bv4[c].y, BL, CC);
                float b2 = fmaf(bv4[c].z, BL, CC);
                float b3 = fmaf(bv4[c].w, BL, CC);
                p[c][0] = exp2f(fmaf(sacc[c][0], SC, b0));
                p[c][1] = exp2f(fmaf(sacc[c][1], SC, b1));
                p[c][2] = exp2f(fmaf(sacc[c][2], SC, b2));
                p[c][3] = exp2f(fmaf(sacc[c][3], SC, b3));
                lrun += p[c][0] + p[c][1] + p[c][2] + p[c][3];
            }
            pa0.u[0] = pack_bf2(p[0][0], p[0][1]);
            pa0.u[1] = pack_bf2(p[0][2], p[0][3]);
            pa0.u[2] = pack_bf2(p[1][0], p[1][1]);
            pa0.u[3] = pack_bf2(p[1][2], p[1][3]);
            pa1.u[0] = pack_bf2(p[2][0], p[2][1]);
            pa1.u[1] = pack_bf2(p[2][2], p[2][3]);
            pa1.u[2] = pack_bf2(p[3][0], p[3][1]);
            pa1.u[3] = pack_bf2(p[3][2], p[3][3]);
        }

        // rotate buffers
        bPV = bQK; bQK = bST; bST = (bST == 2) ? 0 : bST + 1;
    }

    // ---- epilogue: PV for the last tile ----
    {
        const char* v0 = (const char*)&lV[bPV][0];
        const char* v1 = v0 + 4096;
        u16x4 ra0[4], rb0[4], ra1[4], rb1[4];
#pragma unroll
        for (int c = 0; c < 4; ++c) {
            unsigned ad = (unsigned)(unsigned long long)(v0 + c * 1024) + lane * 8;
            asm volatile("ds_read_b64_tr_b16 %0, %1" : "=&v"(ra0[c]) : "v"(ad));
            asm volatile("ds_read_b64_tr_b16 %0, %1 offset:512" : "=&v"(rb0[c]) : "v"(ad));
        }
#pragma unroll
        for (int c = 0; c < 4; ++c) {
            unsigned ad = (unsigned)(unsigned long long)(v1 + c * 1024) + lane * 8;
            asm volatile("ds_read_b64_tr_b16 %0, %1" : "=&v"(ra1[c]) : "v"(ad));
            asm volatile("ds_read_b64_tr_b16 %0, %1 offset:512" : "=&v"(rb1[c]) : "v"(ad));
        }
        asm volatile("s_waitcnt lgkmcnt(0)" ::: "memory");
        __builtin_amdgcn_sched_barrier(0);
        __builtin_amdgcn_s_setprio(1);
#pragma unroll
        for (int c = 0; c < 4; ++c) {
            union { u16x4 h2[2]; bf16x8 v8; } u;
            u.h2[0] = ra0[c]; u.h2[1] = rb0[c];
            oacc[c] = __builtin_amdgcn_mfma_f32_16x16x32_bf16(pa0.v, u.v8, oacc[c], 0, 0, 0);
        }
#pragma unroll
        for (int c = 0; c < 4; ++c) {
            union { u16x4 h2[2]; bf16x8 v8; } u;
            u.h2[0] = ra1[c]; u.h2[1] = rb1[c];
            oacc[c] = __builtin_amdgcn_mfma_f32_16x16x32_bf16(pa1.v, u.v8, oacc[c], 0, 0, 0);
        }
        __builtin_amdgcn_s_setprio(0);
    }

    lrun += __shfl_xor(lrun, 16);
    lrun += __shfl_xor(lrun, 32);
    float linv = 1.f / lrun;
    float lo[4];
#pragma unroll
    for (int j = 0; j < 4; ++j) lo[j] = __shfl(linv, fq * 4 + j);
#pragma unroll
    for (int c = 0; c < 4; ++c)
#pragma unroll
        for (int j = 0; j < 4; ++j) {
            int row = q0 + w * 16 + fq * 4 + j;
            int d = c * 16 + fr;
            O[obase + (size_t)row * H + d] = f2bf(oacc[c][j] * lo[j]);
        }
}

extern "C" void kernel_launch(void* const* d_in, const int* in_sizes, int n_in,
                              void* d_out, int out_size, void* d_ws, size_t ws_size,
                              hipStream_t stream) {
    const float* x    = (const float*)d_in[0];
    const float* ab   = (const float*)d_in[1];
    const float* ln1g = (const float*)d_in[2];
    const float* ln1b = (const float*)d_in[3];
    const float* Wq   = (const float*)d_in[4];
    const float* bq   = (const float*)d_in[5];
    const float* Wk   = (const float*)d_in[6];
    const float* bk   = (const float*)d_in[7];
    const float* Wv   = (const float*)d_in[8];
    const float* bv   = (const float*)d_in[9];
    const float* Wo   = (const float*)d_in[10];
    const float* bo   = (const float*)d_in[11];
    const float* ln2g = (const float*)d_in[12];
    const float* ln2b = (const float*)d_in[13];
    const float* W1   = (const float*)d_in[14];
    const float* b1   = (const float*)d_in[15];
    const float* W2   = (const float*)d_in[16];
    const float* b2   = (const float*)d_in[17];

    char* ws = (char*)d_ws;
    size_t off = 0;
    auto alloc = [&](size_t bytes) -> void* {
        void* p = ws + off;
        off += (bytes + 255) & ~(size_t)255;
        return p;
    };
    unsigned short* Wqt = (unsigned short*)alloc((size_t)H * H * 2); // q,k,v contiguous
    unsigned short* Wkt = (unsigned short*)alloc((size_t)H * H * 2);
    unsigned short* Wvt = (unsigned short*)alloc((size_t)H * H * 2);
    unsigned short* Wot = (unsigned short*)alloc((size_t)H * H * 2);
    unsigned short* W1t = (unsigned short*)alloc((size_t)H * FF * 2);
    unsigned short* W2t = (unsigned short*)alloc((size_t)H * FF * 2);
    float* bqkv        = (float*)alloc((size_t)QS * 4);
    unsigned short* ybuf = (unsigned short*)alloc((size_t)Mrows * H * 2);
    unsigned short* qkvb = (unsigned short*)alloc((size_t)Mrows * QS * 2);
    unsigned short* ob = (unsigned short*)alloc((size_t)Mrows * H * 2);
    unsigned short* hb = (unsigned short*)alloc((size_t)Mrows * FF * 2);
    (void)ws_size; (void)in_sizes; (void)n_in; (void)out_size;
    (void)Wkt; (void)Wvt;

    dim3 tb(32, 8, 1);
    wcvt_all<<<dim3(12288), tb, 0, stream>>>(Wq, Wk, Wv, Wo, W1, W2, Wqt, Wot, W1t, W2t);
    catbias<<<QS / 256, 256, 0, stream>>>(bq, bk, bv, bqkv);

    ln_kernel<<<Mrows, 256, 0, stream>>>(x, ln1g, ln1b, ybuf);

    // fused QKV projection: [8192,1024] @ [1024,3072]
    gemm8p128<0><<<dim3((Mrows / 128) * (QS / 256)), 512, 0, stream>>>(ybuf, Wqt, bqkv, nullptr, qkvb, QS, H);

    attn_kernel<<<dim3(Bb * NH * (S / 128)), 512, 0, stream>>>(qkvb, ab, ob);

    // Wo + residual: [8192,1024] @ [1024,1024] -> f32 d_out
    gemm8p128<2><<<dim3((Mrows / 128) * (H / 256)), 512, 0, stream>>>(ob, Wot, bo, x, d_out, H, H);

    ln_kernel<<<Mrows, 256, 0, stream>>>((const float*)d_out, ln2g, ln2b, ybuf);

    // FFN1: [8192,1024] @ [1024,4096] + gelu
    gemm8p<1><<<dim3((Mrows / 256) * (FF / 256)), 512, 0, stream>>>(ybuf, W1t, b1, hb, FF, H);

    // FFN2 + residual: [8192,4096] @ [4096,1024] -> f32 d_out
    gemm8p128<2><<<dim3((Mrows / 128) * (H / 256)), 512, 0, stream>>>(hb, W2t, b2, (const float*)d_out, d_out, H, FF);
}

// Round 16
// 511.422 us; speedup vs baseline: 1.0993x; 1.0096x over previous
//
#include <hip/hip_runtime.h>

#define DEVINL __device__ __forceinline__

typedef __bf16 bf16x8 __attribute__((ext_vector_type(8)));
typedef float f32x4 __attribute__((ext_vector_type(4)));
typedef unsigned short u16x4 __attribute__((ext_vector_type(4)));

static constexpr int Bb = 4, S = 2048, H = 1024, NH = 16, DK = 64, FF = 4096;
static constexpr int Mrows = Bb * S; // 8192
static constexpr int QS = 3 * H;    // fused QKV row stride

DEVINL unsigned short f2bf(float f) {
    union { __bf16 b; unsigned short u; } r;
    r.b = (__bf16)f;
    return r.u;
}

DEVINL unsigned pack_bf2(float a, float b) {
    union { __bf16 h[2]; unsigned u; } r;
    r.h[0] = (__bf16)a; r.h[1] = (__bf16)b;
    return r.u;
}

DEVINL void gld16(const void* g, void* l) {
    auto gp = reinterpret_cast<const __attribute__((address_space(1))) unsigned*>(
        reinterpret_cast<unsigned long long>(g));
    auto lp = reinterpret_cast<__attribute__((address_space(3))) unsigned*>(
        (unsigned)reinterpret_cast<unsigned long long>(l));
    __builtin_amdgcn_global_load_lds(gp, lp, 16, 0, 0);
}

// ---------------- merged weight convert + qkv bias concat, one launch -------
__global__ __launch_bounds__(256)
void wcvt_all(const float* __restrict__ Wq, const float* __restrict__ Wk,
              const float* __restrict__ Wv, const float* __restrict__ Wo,
              const float* __restrict__ W1, const float* __restrict__ W2,
              const float* __restrict__ bq, const float* __restrict__ bk2,
              const float* __restrict__ bv2,
              unsigned short* __restrict__ Wqt, unsigned short* __restrict__ Wot,
              unsigned short* __restrict__ W1t, unsigned short* __restrict__ W2t,
              float* __restrict__ bqkv) {
    int id = blockIdx.x;
    if (id >= 12288) { // bias concat: 12 blocks x 256 elems
        int i = (id - 12288) * 256 + threadIdx.y * 32 + threadIdx.x;
        float v = (i < 1024) ? bq[i] : (i < 2048 ? bk2[i - 1024] : bv2[i - 2048]);
        bqkv[i] = v;
        return;
    }
    const float* in; unsigned short* out; int K, N;
    if (id < 3072) {
        int which = id >> 10; id &= 1023;
        in = which == 0 ? Wq : (which == 1 ? Wk : Wv);
        out = Wqt + (size_t)which * H * H; K = H; N = H;
    } else if (id < 4096) { in = Wo; out = Wot; K = H; N = H; id -= 3072; }
    else if (id < 8192)   { in = W1; out = W1t; K = H; N = FF; id -= 4096; }
    else                  { in = W2; out = W2t; K = FF; N = H; id -= 8192; }
    const int nx = N / 32;
    const int n0 = (id % nx) * 32, k0 = (id / nx) * 32;

    __shared__ float t[32][33];
    int tx = threadIdx.x, ty = threadIdx.y;
#pragma unroll
    for (int i = 0; i < 32; i += 8) t[ty + i][tx] = in[(size_t)(k0 + ty + i) * N + n0 + tx];
    __syncthreads();
#pragma unroll
    for (int i = 0; i < 32; i += 8) out[(size_t)(n0 + ty + i) * K + k0 + tx] = f2bf(t[tx][ty + i]);
}

// ---------------- LayerNorm: f32 row -> bf16 row ----------------
__global__ __launch_bounds__(256)
void ln_kernel(const float* __restrict__ x, const float* __restrict__ g,
               const float* __restrict__ be, unsigned short* __restrict__ y) {
    int row = blockIdx.x, tid = threadIdx.x;
    const float4 v = ((const float4*)(x + (size_t)row * H))[tid];
    float s = v.x + v.y + v.z + v.w;
    float ss = v.x * v.x + v.y * v.y + v.z * v.z + v.w * v.w;
#pragma unroll
    for (int m = 1; m < 64; m <<= 1) { s += __shfl_xor(s, m); ss += __shfl_xor(ss, m); }
    __shared__ float red[2][4];
    int lane = tid & 63, w = tid >> 6;
    if (lane == 0) { red[0][w] = s; red[1][w] = ss; }
    __syncthreads();
    s = red[0][0] + red[0][1] + red[0][2] + red[0][3];
    ss = red[1][0] + red[1][1] + red[1][2] + red[1][3];
    float mean = s * (1.f / H);
    float var = ss * (1.f / H) - mean * mean;
    float rstd = rsqrtf(var + 1e-5f);
    float4 gv = ((const float4*)g)[tid];
    float4 bv = ((const float4*)be)[tid];
    ushort4 o;
    o.x = f2bf((v.x - mean) * rstd * gv.x + bv.x);
    o.y = f2bf((v.y - mean) * rstd * gv.y + bv.y);
    o.z = f2bf((v.z - mean) * rstd * gv.z + bv.z);
    o.w = f2bf((v.w - mean) * rstd * gv.w + bv.w);
    ((ushort4*)(y + (size_t)row * H))[tid] = o;
}

// ---------------- 256x256 8-phase GEMM (T2+T3+T4+T5), quadrant schedule ------
// EPI: 0 = store bf16, 1 = gelu->bf16
template <int EPI>
__global__ __launch_bounds__(512, 2)
void gemm8p(const unsigned short* __restrict__ A, const unsigned short* __restrict__ Bt,
            const float* __restrict__ bias, void* __restrict__ outp, int N, int K) {
    __shared__ __align__(16) char lds[131072];
    const int tid = threadIdx.x, lane = tid & 63, w = tid >> 6;
    const int wm = w >> 2, wn = w & 3;
    const int fr = lane & 15, fq = lane >> 4;
    const int nwg = gridDim.x, id = blockIdx.x;
    const int swz = (id & 7) * (nwg >> 3) + (id >> 3);
    const int m0 = (swz & 31) * 256, n0 = (swz >> 5) * 256;

    int srow[2], scol[2];
#pragma unroll
    for (int l = 0; l < 2; ++l) {
        int idx = l * 512 + tid;
        srow[l] = idx >> 3;
        scol[l] = ((idx & 7) ^ (srow[l] & 7)) * 8;
    }
    const int NT = K >> 6;

    auto stage = [&](int ht, int buf, int kt) {
        const unsigned short* src = (ht < 2) ? A : Bt;
        const int hh = ht & 1;
        char* dst = lds + ((ht < 2 ? 0 : 65536) + (buf * 2 + hh) * 16384);
        const int rbase = ((ht < 2) ? m0 : n0) + hh * 128;
        const int kb = kt * 64;
#pragma unroll
        for (int l = 0; l < 2; ++l)
            gld16(src + (size_t)(rbase + srow[l]) * K + kb + scol[l],
                  dst + (size_t)(l * 512 + tid) * 16);
    };

    int oa[2];
#pragma unroll
    for (int ks = 0; ks < 2; ++ks)
        oa[ks] = fr * 128 + (((ks * 4 + fq) ^ (fr & 7)) & 7) * 16;
    const int aBase0 = wm * 16384;
    const int bBase0 = 65536 + (wn >> 1) * 16384 + (wn & 1) * 8192;

    f32x4 acc[8][4] = {};
    bf16x8 aF[4][2], bF[4][2];

    stage(0, 0, 0); stage(1, 0, 0); stage(2, 0, 0); stage(3, 0, 0);
    if (NT > 1) {
        stage(0, 1, 1);
        asm volatile("s_waitcnt vmcnt(2)" ::: "memory");
    } else {
        asm volatile("s_waitcnt vmcnt(0)" ::: "memory");
    }
    __builtin_amdgcn_s_barrier();

    int buf = 0;
    for (int t = 0; t < NT; ++t, buf ^= 1) {
        const char* Ar = lds + aBase0 + buf * 32768;
        const char* Br = lds + bBase0 + buf * 32768;

#pragma unroll
        for (int mb = 0; mb < 4; ++mb)
#pragma unroll
            for (int ks = 0; ks < 2; ++ks)
                aF[mb][ks] = *(const bf16x8*)(Ar + mb * 2048 + oa[ks]);
#pragma unroll
        for (int nb = 0; nb < 2; ++nb)
#pragma unroll
            for (int ks = 0; ks < 2; ++ks)
                bF[nb][ks] = *(const bf16x8*)(Br + nb * 2048 + oa[ks]);
        if (t + 1 < NT) stage(1, buf ^ 1, t + 1);
        __builtin_amdgcn_s_barrier();
        asm volatile("s_waitcnt lgkmcnt(0)" ::: "memory");
        __builtin_amdgcn_sched_barrier(0);
        __builtin_amdgcn_s_setprio(1);
#pragma unroll
        for (int mb = 0; mb < 4; ++mb)
#pragma unroll
            for (int nb = 0; nb < 2; ++nb)
#pragma unroll
                for (int ks = 0; ks < 2; ++ks)
                    acc[mb][nb] = __builtin_amdgcn_mfma_f32_16x16x32_bf16(aF[mb][ks], bF[nb][ks], acc[mb][nb], 0, 0, 0);
        __builtin_amdgcn_s_setprio(0);
        __builtin_amdgcn_s_barrier();

#pragma unroll
        for (int nb = 2; nb < 4; ++nb)
#pragma unroll
            for (int ks = 0; ks < 2; ++ks)
                bF[nb][ks] = *(const bf16x8*)(Br + nb * 2048 + oa[ks]);
        if (t + 1 < NT) stage(2, buf ^ 1, t + 1);
        __builtin_amdgcn_s_barrier();
        asm volatile("s_waitcnt lgkmcnt(0)" ::: "memory");
        __builtin_amdgcn_sched_barrier(0);
        __builtin_amdgcn_s_setprio(1);
#pragma unroll
        for (int mb = 0; mb < 4; ++mb)
#pragma unroll
            for (int nb = 2; nb < 4; ++nb)
#pragma unroll
                for (int ks = 0; ks < 2; ++ks)
                    acc[mb][nb] = __builtin_amdgcn_mfma_f32_16x16x32_bf16(aF[mb][ks], bF[nb][ks], acc[mb][nb], 0, 0, 0);
        __builtin_amdgcn_s_setprio(0);
        __builtin_amdgcn_s_barrier();

#pragma unroll
        for (int mb = 0; mb < 4; ++mb)
#pragma unroll
            for (int ks = 0; ks < 2; ++ks)
                aF[mb][ks] = *(const bf16x8*)(Ar + 8192 + mb * 2048 + oa[ks]);
        if (t + 1 < NT) stage(3, buf ^ 1, t + 1);
        __builtin_amdgcn_s_barrier();
        asm volatile("s_waitcnt lgkmcnt(0)" ::: "memory");
        __builtin_amdgcn_sched_barrier(0);
        __builtin_amdgcn_s_setprio(1);
#pragma unroll
        for (int mb = 0; mb < 4; ++mb)
#pragma unroll
            for (int nb = 0; nb < 2; ++nb)
#pragma unroll
                for (int ks = 0; ks < 2; ++ks)
                    acc[4 + mb][nb] = __builtin_amdgcn_mfma_f32_16x16x32_bf16(aF[mb][ks], bF[nb][ks], acc[4 + mb][nb], 0, 0, 0);
        __builtin_amdgcn_s_setprio(0);
        __builtin_amdgcn_s_barrier();

        if (t + 2 < NT) {
            stage(0, buf, t + 2);
            asm volatile("s_waitcnt vmcnt(2)" ::: "memory");
        } else if (t + 1 < NT) {
            asm volatile("s_waitcnt vmcnt(0)" ::: "memory");
        }
        __builtin_amdgcn_s_barrier();
        __builtin_amdgcn_s_setprio(1);
#pragma unroll
        for (int mb = 0; mb < 4; ++mb)
#pragma unroll
            for (int nb = 2; nb < 4; ++nb)
#pragma unroll
                for (int ks = 0; ks < 2; ++ks)
                    acc[4 + mb][nb] = __builtin_amdgcn_mfma_f32_16x16x32_bf16(aF[mb][ks], bF[nb][ks], acc[4 + mb][nb], 0, 0, 0);
        __builtin_amdgcn_s_setprio(0);
        __builtin_amdgcn_s_barrier();
    }

#pragma unroll
    for (int mb = 0; mb < 8; ++mb) {
        int row0 = m0 + wm * 128 + mb * 16 + fq * 4;
#pragma unroll
        for (int nb = 0; nb < 4; ++nb) {
            int col = n0 + wn * 64 + nb * 16 + fr;
            float bz = bias[col];
#pragma unroll
            for (int j = 0; j < 4; ++j) {
                float vv = acc[mb][nb][j] + bz;
                size_t idx = (size_t)(row0 + j) * N + col;
                if (EPI == 0) {
                    ((unsigned short*)outp)[idx] = f2bf(vv);
                } else {
                    float tg = 0.5f * vv * (1.f + erff(vv * 0.70710678118654752f));
                    ((unsigned short*)outp)[idx] = f2bf(tg);
                }
            }
        }
    }
}

// ---------------- 128x256 8-phase GEMM -----------------
// EPI: 0 = bf16 + bias; 2 = f32 + bias + resid
template <int EPI>
__global__ __launch_bounds__(512, 2)
void gemm8p128(const unsigned short* __restrict__ A, const unsigned short* __restrict__ Bt,
               const float* __restrict__ bias, const float* __restrict__ resid,
               void* __restrict__ outp, int N, int K) {
    __shared__ __align__(16) char lds[98304];
    const int tid = threadIdx.x, lane = tid & 63, w = tid >> 6;
    const int wm = w >> 2, wn = w & 3;
    const int fr = lane & 15, fq = lane >> 4;
    const int nwg = gridDim.x, id = blockIdx.x;
    const int swz = (id & 7) * (nwg >> 3) + (id >> 3);
    const int m0 = (swz & 63) * 128, n0 = (swz >> 6) * 256;

    int srow[2], scol[2];
#pragma unroll
    for (int l = 0; l < 2; ++l) {
        int idx = l * 512 + tid;
        srow[l] = idx >> 3;
        scol[l] = ((idx & 7) ^ (srow[l] & 7)) * 8;
    }
    const int NT = K >> 6;

    auto stageA = [&](int buf, int kt) {
        char* dst = lds + buf * 16384;
#pragma unroll
        for (int l = 0; l < 2; ++l)
            gld16(A + (size_t)(m0 + srow[l]) * K + kt * 64 + scol[l],
                  dst + (size_t)(l * 512 + tid) * 16);
    };
    auto stageB = [&](int hh, int buf, int kt) {
        char* dst = lds + 32768 + buf * 32768 + hh * 16384;
#pragma unroll
        for (int l = 0; l < 2; ++l)
            gld16(Bt + (size_t)(n0 + hh * 128 + srow[l]) * K + kt * 64 + scol[l],
                  dst + (size_t)(l * 512 + tid) * 16);
    };

    int oa[2];
#pragma unroll
    for (int ks = 0; ks < 2; ++ks)
        oa[ks] = fr * 128 + (((ks * 4 + fq) ^ (fr & 7)) & 7) * 16;
    const int aWB = wm * 8192;
    const int bWB = (wn >> 1) * 16384 + (wn & 1) * 8192;

    f32x4 acc[4][4] = {};
    bf16x8 aF[2][2], bF[4][2];

    stageA(0, 0); stageB(0, 0, 0); stageB(1, 0, 0);
    if (NT > 1) {
        stageA(1, 1);
        asm volatile("s_waitcnt vmcnt(2)" ::: "memory");
    } else {
        asm volatile("s_waitcnt vmcnt(0)" ::: "memory");
    }
    __builtin_amdgcn_s_barrier();

    int buf = 0;
    for (int t = 0; t < NT; ++t, buf ^= 1) {
        const char* Ar = lds + buf * 16384 + aWB;
        const char* Br = lds + 32768 + buf * 32768 + bWB;

#pragma unroll
        for (int mb = 0; mb < 2; ++mb)
#pragma unroll
            for (int ks = 0; ks < 2; ++ks)
                aF[mb][ks] = *(const bf16x8*)(Ar + mb * 2048 + oa[ks]);
#pragma unroll
        for (int nb = 0; nb < 2; ++nb)
#pragma unroll
            for (int ks = 0; ks < 2; ++ks)
                bF[nb][ks] = *(const bf16x8*)(Br + nb * 2048 + oa[ks]);
        if (t + 1 < NT) stageB(0, buf ^ 1, t + 1);
        __builtin_amdgcn_s_barrier();
        asm volatile("s_waitcnt lgkmcnt(0)" ::: "memory");
        __builtin_amdgcn_sched_barrier(0);
        __builtin_amdgcn_s_setprio(1);
#pragma unroll
        for (int mb = 0; mb < 2; ++mb)
#pragma unroll
            for (int nb = 0; nb < 2; ++nb)
#pragma unroll
                for (int ks = 0; ks < 2; ++ks)
                    acc[mb][nb] = __builtin_amdgcn_mfma_f32_16x16x32_bf16(aF[mb][ks], bF[nb][ks], acc[mb][nb], 0, 0, 0);
        __builtin_amdgcn_s_setprio(0);
        __builtin_amdgcn_s_barrier();

#pragma unroll
        for (int nb = 2; nb < 4; ++nb)
#pragma unroll
            for (int ks = 0; ks < 2; ++ks)
                bF[nb][ks] = *(const bf16x8*)(Br + nb * 2048 + oa[ks]);
        if (t + 1 < NT) stageB(1, buf ^ 1, t + 1);
        __builtin_amdgcn_s_barrier();
        asm volatile("s_waitcnt lgkmcnt(0)" ::: "memory");
        __builtin_amdgcn_sched_barrier(0);
        __builtin_amdgcn_s_setprio(1);
#pragma unroll
        for (int mb = 0; mb < 2; ++mb)
#pragma unroll
            for (int nb = 2; nb < 4; ++nb)
#pragma unroll
                for (int ks = 0; ks < 2; ++ks)
                    acc[mb][nb] = __builtin_amdgcn_mfma_f32_16x16x32_bf16(aF[mb][ks], bF[nb][ks], acc[mb][nb], 0, 0, 0);
        __builtin_amdgcn_s_setprio(0);
        __builtin_amdgcn_s_barrier();

#pragma unroll
        for (int mb = 0; mb < 2; ++mb)
#pragma unroll
            for (int ks = 0; ks < 2; ++ks)
                aF[mb][ks] = *(const bf16x8*)(Ar + 4096 + mb * 2048 + oa[ks]);
        __builtin_amdgcn_s_barrier();
        asm volatile("s_waitcnt lgkmcnt(0)" ::: "memory");
        __builtin_amdgcn_sched_barrier(0);
        __builtin_amdgcn_s_setprio(1);
#pragma unroll
        for (int mb = 0; mb < 2; ++mb)
#pragma unroll
            for (int nb = 0; nb < 2; ++nb)
#pragma unroll
                for (int ks = 0; ks < 2; ++ks)
                    acc[2 + mb][nb] = __builtin_amdgcn_mfma_f32_16x16x32_bf16(aF[mb][ks], bF[nb][ks], acc[2 + mb][nb], 0, 0, 0);
        __builtin_amdgcn_s_setprio(0);
        __builtin_amdgcn_s_barrier();

        if (t + 2 < NT) {
            stageA(buf, t + 2);
            asm volatile("s_waitcnt vmcnt(2)" ::: "memory");
        } else if (t + 1 < NT) {
            asm volatile("s_waitcnt vmcnt(0)" ::: "memory");
        }
        __builtin_amdgcn_s_barrier();
        __builtin_amdgcn_s_setprio(1);
#pragma unroll
        for (int mb = 0; mb < 2; ++mb)
#pragma unroll
            for (int nb = 2; nb < 4; ++nb)
#pragma unroll
                for (int ks = 0; ks < 2; ++ks)
                    acc[2 + mb][nb] = __builtin_amdgcn_mfma_f32_16x16x32_bf16(aF[mb][ks], bF[nb][ks], acc[2 + mb][nb], 0, 0, 0);
        __builtin_amdgcn_s_setprio(0);
        __builtin_amdgcn_s_barrier();
    }

#pragma unroll
    for (int mb = 0; mb < 4; ++mb) {
        int row0 = m0 + wm * 64 + mb * 16 + fq * 4;
#pragma unroll
        for (int nb = 0; nb < 4; ++nb) {
            int col = n0 + wn * 64 + nb * 16 + fr;
            float bz = bias[col];
#pragma unroll
            for (int j = 0; j < 4; ++j) {
                size_t idx = (size_t)(row0 + j) * N + col;
                float vv = acc[mb][nb][j] + bz;
                if (EPI == 0) {
                    ((unsigned short*)outp)[idx] = f2bf(vv);
                } else {
                    ((float*)outp)[idx] = vv + resid[idx];
                }
            }
        }
    }
}

// ---------------- flash attention: QBLK=128, fixed-max, zero-shuffle PV ------
// T15 1-deep pipeline + early tr_read issue: tr(kt-1) issued BEFORE QK(kt)
// so tr latency hides under the QK cluster.
__global__ __launch_bounds__(512, 4)
void attn_kernel(const unsigned short* __restrict__ QKV, const float* __restrict__ bias,
                 unsigned short* __restrict__ O) {
    __shared__ __align__(16) unsigned short lK[3][4096];
    __shared__ __align__(16) unsigned short lV[3][4096];
    const int tid = threadIdx.x, lane = tid & 63, w = tid >> 6;
    const int fr = lane & 15, fq = lane >> 4;

    const int bid = blockIdx.x;                   // 1024 blocks
    const int slice = (bid >> 5) * 8 + (bid & 7); // 0..255 = (h, q-tile)
    const int b = (bid >> 3) & 3;                 // 4 bias-sharers same XCD
    const int h = slice >> 4;
    const int q0 = (slice & 15) * 128;

    const size_t base = (size_t)b * S * QS + h * DK;
    const unsigned short* Qp = QKV + base;
    const unsigned short* Kp = QKV + base + H;
    const unsigned short* Vp = QKV + base + 2 * H;
    const size_t obase = (size_t)b * S * H + h * DK;

    bf16x8 aq[2];
    {
        const unsigned short* qp = Qp + (size_t)(q0 + w * 16 + fr) * QS + fq * 8;
        aq[0] = *(const bf16x8*)qp;
        aq[1] = *(const bf16x8*)(qp + 32);
    }

    const int chk = w * 64 + lane;
    const int rK = chk >> 3, cK = ((chk & 7) ^ (rK & 7)) * 8;
    int vk, vd;
    {
        int ch = chk;
        int dch = ch & 1, j = (ch >> 1) & 3, fqi = (ch >> 3) & 3, half = (ch >> 5) & 1,
            c = (ch >> 6) & 3, ks = (ch >> 8) & 1;
        vk = ks * 32 + half * 16 + fqi * 4 + j; vd = c * 16 + dch * 8;
    }

    f32x4 oacc[4] = {};
    float lrun = 0.f;
    const float* bias_q = bias + (size_t)h * S * S + (size_t)(q0 + w * 16 + fr) * S;

    const float SC = 0.18033688f;       // 0.125 * log2(e)
    const float BL = 1.44269504f;       // log2(e)
    const float CC = -23.08312065f;     // -16 * log2(e)

    auto stage = [&](int buf, int k0) {
        gld16(Kp + (size_t)(k0 + rK) * QS + cK, &lK[buf][w * 512]);
        gld16(Vp + (size_t)(k0 + vk) * QS + vd, &lV[buf][w * 512]);
    };

    union pa_t { unsigned u[4]; bf16x8 v; };
    pa_t pa0, pa1; // loop-carried packed P for the previous tile

    stage(0, 0);
    __syncthreads();       // tile0 staged
    stage(1, 64);          // tile1 in flight

    // ---- prologue: tile 0 QK + softmax (no PV yet) ----
    {
        float4 bv4[4];
#pragma unroll
        for (int c = 0; c < 4; ++c)
            bv4[c] = *(const float4*)(bias_q + c * 16 + fq * 4);
        f32x4 sacc[4] = {};
        __builtin_amdgcn_s_setprio(1);
#pragma unroll
        for (int c = 0; c < 4; ++c) {
            int row = c * 16 + fr;
#pragma unroll
            for (int dh = 0; dh < 2; ++dh) {
                bf16x8 bk = *(const bf16x8*)((char*)&lK[0][0] +
                    ((row * 128 + dh * 64 + fq * 16) ^ ((row & 7) << 4)));
                sacc[c] = __builtin_amdgcn_mfma_f32_16x16x32_bf16(bk, aq[dh], sacc[c], 0, 0, 0);
            }
        }
        __builtin_amdgcn_s_setprio(0);
        float p[4][4];
#pragma unroll
        for (int c = 0; c < 4; ++c) {
            float b0 = fmaf(bv4[c].x, BL, CC);
            float b1 = fmaf(bv4[c].y, BL, CC);
            float b2 = fmaf(bv4[c].z, BL, CC);
            float b3 = fmaf(bv4[c].w, BL, CC);
            p[c][0] = exp2f(fmaf(sacc[c][0], SC, b0));
            p[c][1] = exp2f(fmaf(sacc[c][1], SC, b1));
            p[c][2] = exp2f(fmaf(sacc[c][2], SC, b2));
            p[c][3] = exp2f(fmaf(sacc[c][3], SC, b3));
            lrun += p[c][0] + p[c][1] + p[c][2] + p[c][3];
        }
        pa0.u[0] = pack_bf2(p[0][0], p[0][1]);
        pa0.u[1] = pack_bf2(p[0][2], p[0][3]);
        pa0.u[2] = pack_bf2(p[1][0], p[1][1]);
        pa0.u[3] = pack_bf2(p[1][2], p[1][3]);
        pa1.u[0] = pack_bf2(p[2][0], p[2][1]);
        pa1.u[1] = pack_bf2(p[2][2], p[2][3]);
        pa1.u[2] = pack_bf2(p[3][0], p[3][1]);
        pa1.u[3] = pack_bf2(p[3][2], p[3][3]);
    }

    int bST = 2, bQK = 1, bPV = 0;
    for (int kt = 1; kt < S / 64; ++kt) {
        __syncthreads();   // buf[bQK] staged; prev iter's reads of buf[bST] done
        if (kt + 1 < S / 64) stage(bST, (kt + 1) * 64);

        float4 bv4[4];
#pragma unroll
        for (int c = 0; c < 4; ++c)
            bv4[c] = *(const float4*)(bias_q + kt * 64 + c * 16 + fq * 4);

        // EARLY: issue tr reads for PV(kt-1); latency hides under QK cluster
        u16x4 ra0[4], rb0[4], ra1[4], rb1[4];
        {
            const char* v0 = (const char*)&lV[bPV][0];
            const char* v1 = v0 + 4096;
#pragma unroll
            for (int c = 0; c < 4; ++c) {
                unsigned ad = (unsigned)(unsigned long long)(v0 + c * 1024) + lane * 8;
                asm volatile("ds_read_b64_tr_b16 %0, %1" : "=&v"(ra0[c]) : "v"(ad));
                asm volatile("ds_read_b64_tr_b16 %0, %1 offset:512" : "=&v"(rb0[c]) : "v"(ad));
            }
#pragma unroll
            for (int c = 0; c < 4; ++c) {
                unsigned ad = (unsigned)(unsigned long long)(v1 + c * 1024) + lane * 8;
                asm volatile("ds_read_b64_tr_b16 %0, %1" : "=&v"(ra1[c]) : "v"(ad));
                asm volatile("ds_read_b64_tr_b16 %0, %1 offset:512" : "=&v"(rb1[c]) : "v"(ad));
            }
        }
        __builtin_amdgcn_sched_barrier(0); // pin: tr issues precede QK cluster

        // QK for tile kt (compiler lgkm waits conservatively cover the tr reads)
        f32x4 sacc[4] = {};
        __builtin_amdgcn_s_setprio(1);
#pragma unroll
        for (int c = 0; c < 4; ++c) {
            int row = c * 16 + fr;
#pragma unroll
            for (int dh = 0; dh < 2; ++dh) {
                bf16x8 bk = *(const bf16x8*)((char*)&lK[bQK][0] +
                    ((row * 128 + dh * 64 + fq * 16) ^ ((row & 7) << 4)));
                sacc[c] = __builtin_amdgcn_mfma_f32_16x16x32_bf16(bk, aq[dh], sacc[c], 0, 0, 0);
            }
        }
        __builtin_amdgcn_s_setprio(0);

        // PV for tile kt-1 (tr data already in regs)
        {
            asm volatile("s_waitcnt lgkmcnt(0)" ::: "memory");
            __builtin_amdgcn_sched_barrier(0);
            __builtin_amdgcn_s_setprio(1);
#pragma unroll
            for (int c = 0; c < 4; ++c) {
                union { u16x4 h2[2]; bf16x8 v8; } u;
                u.h2[0] = ra0[c]; u.h2[1] = rb0[c];
                oacc[c] = __builtin_amdgcn_mfma_f32_16x16x32_bf16(pa0.v, u.v8, oacc[c], 0, 0, 0);
            }
#pragma unroll
            for (int c = 0; c < 4; ++c) {
                union { u16x4 h2[2]; bf16x8 v8; } u;
                u.h2[0] = ra1[c]; u.h2[1] = rb1[c];
                oacc[c] = __builtin_amdgcn_mfma_f32_16x16x32_bf16(pa1.v, u.v8, oacc[c], 0, 0, 0);
            }
            __builtin_amdgcn_s_setprio(0);
            __builtin_amdgcn_sched_barrier(0);
        }

        // softmax for tile kt -> pa0/pa1 (overlaps PV MFMA drain)
        {
            float p[4][4];
#pragma unroll
            for (int c = 0; c < 4; ++c) {
                float b0 = fmaf(bv4[c].x, BL, CC);
                float b1 = fmaf(bv4[c].y, BL, CC);
                float b2 = fmaf(bv4[c].z, BL, CC);
                float b3 = fmaf(bv4[c].w, BL, CC);
                p[c][0] = exp2f(fmaf(sacc[c][0], SC, b0));
                p[c][1] = exp2f(fmaf(sacc[c][1], SC, b1));
                p[c][2] = exp2f(fmaf(sacc[c][2], SC, b2));
                p[c][3] = exp2f(fmaf(sacc[c][3], SC, b3));
                lrun += p[c][0] + p[c][1] + p[c][2] + p[c][3];
            }
            pa0.u[0] = pack_bf2(p[0][0], p[0][1]);
            pa0.u[1] = pack_bf2(p[0][2], p[0][3]);
            pa0.u[2] = pack_bf2(p[1][0], p[1][1]);
            pa0.u[3] = pack_bf2(p[1][2], p[1][3]);
            pa1.u[0] = pack_bf2(p[2][0], p[2][1]);
            pa1.u[1] = pack_bf2(p[2][2], p[2][3]);
            pa1.u[2] = pack_bf2(p[3][0], p[3][1]);
            pa1.u[3] = pack_bf2(p[3][2], p[3][3]);
        }

        // rotate buffers
        bPV = bQK; bQK = bST; bST = (bST == 2) ? 0 : bST + 1;
    }

    // ---- epilogue: PV for the last tile ----
    {
        const char* v0 = (const char*)&lV[bPV][0];
        const char* v1 = v0 + 4096;
        u16x4 ra0[4], rb0[4], ra1[4], rb1[4];
#pragma unroll
        for (int c = 0; c < 4; ++c) {
            unsigned ad = (unsigned)(unsigned long long)(v0 + c * 1024) + lane * 8;
            asm volatile("ds_read_b64_tr_b16 %0, %1" : "=&v"(ra0[c]) : "v"(ad));
            asm volatile("ds_read_b64_tr_b16 %0, %1 offset:512" : "=&v"(rb0[c]) : "v"(ad));
        }
#pragma unroll
        for (int c = 0; c < 4; ++c) {
            unsigned ad = (unsigned)(unsigned long long)(v1 + c * 1024) + lane * 8;
            asm volatile("ds_read_b64_tr_b16 %0, %1" : "=&v"(ra1[c]) : "v"(ad));
            asm volatile("ds_read_b64_tr_b16 %0, %1 offset:512" : "=&v"(rb1[c]) : "v"(ad));
        }
        asm volatile("s_waitcnt lgkmcnt(0)" ::: "memory");
        __builtin_amdgcn_sched_barrier(0);
        __builtin_amdgcn_s_setprio(1);
#pragma unroll
        for (int c = 0; c < 4; ++c) {
            union { u16x4 h2[2]; bf16x8 v8; } u;
            u.h2[0] = ra0[c]; u.h2[1] = rb0[c];
            oacc[c] = __builtin_amdgcn_mfma_f32_16x16x32_bf16(pa0.v, u.v8, oacc[c], 0, 0, 0);
        }
#pragma unroll
        for (int c = 0; c < 4; ++c) {
            union { u16x4 h2[2]; bf16x8 v8; } u;
            u.h2[0] = ra1[c]; u.h2[1] = rb1[c];
            oacc[c] = __builtin_amdgcn_mfma_f32_16x16x32_bf16(pa1.v, u.v8, oacc[c], 0, 0, 0);
        }
        __builtin_amdgcn_s_setprio(0);
    }

    lrun += __shfl_xor(lrun, 16);
    lrun += __shfl_xor(lrun, 32);
    float linv = 1.f / lrun;
    float lo[4];
#pragma unroll
    for (int j = 0; j < 4; ++j) lo[j] = __shfl(linv, fq * 4 + j);
#pragma unroll
    for (int c = 0; c < 4; ++c)
#pragma unroll
        for (int j = 0; j < 4; ++j) {
            int row = q0 + w * 16 + fq * 4 + j;
            int d = c * 16 + fr;
            O[obase + (size_t)row * H + d] = f2bf(oacc[c][j] * lo[j]);
        }
}

extern "C" void kernel_launch(void* const* d_in, const int* in_sizes, int n_in,
                              void* d_out, int out_size, void* d_ws, size_t ws_size,
                              hipStream_t stream) {
    const float* x    = (const float*)d_in[0];
    const float* ab   = (const float*)d_in[1];
    const float* ln1g = (const float*)d_in[2];
    const float* ln1b = (const float*)d_in[3];
    const float* Wq   = (const float*)d_in[4];
    const float* bq   = (const float*)d_in[5];
    const float* Wk   = (const float*)d_in[6];
    const float* bk   = (const float*)d_in[7];
    const float* Wv   = (const float*)d_in[8];
    const float* bv   = (const float*)d_in[9];
    const float* Wo   = (const float*)d_in[10];
    const float* bo   = (const float*)d_in[11];
    const float* ln2g = (const float*)d_in[12];
    const float* ln2b = (const float*)d_in[13];
    const float* W1   = (const float*)d_in[14];
    const float* b1   = (const float*)d_in[15];
    const float* W2   = (const float*)d_in[16];
    const float* b2   = (const float*)d_in[17];

    char* ws = (char*)d_ws;
    size_t off = 0;
    auto alloc = [&](size_t bytes) -> void* {
        void* p = ws + off;
        off += (bytes + 255) & ~(size_t)255;
        return p;
    };
    unsigned short* Wqt = (unsigned short*)alloc((size_t)H * H * 2); // q,k,v contiguous
    unsigned short* Wkt = (unsigned short*)alloc((size_t)H * H * 2);
    unsigned short* Wvt = (unsigned short*)alloc((size_t)H * H * 2);
    unsigned short* Wot = (unsigned short*)alloc((size_t)H * H * 2);
    unsigned short* W1t = (unsigned short*)alloc((size_t)H * FF * 2);
    unsigned short* W2t = (unsigned short*)alloc((size_t)H * FF * 2);
    float* bqkv        = (float*)alloc((size_t)QS * 4);
    unsigned short* ybuf = (unsigned short*)alloc((size_t)Mrows * H * 2);
    unsigned short* qkvb = (unsigned short*)alloc((size_t)Mrows * QS * 2);
    unsigned short* ob = (unsigned short*)alloc((size_t)Mrows * H * 2);
    unsigned short* hb = (unsigned short*)alloc((size_t)Mrows * FF * 2);
    (void)ws_size; (void)in_sizes; (void)n_in; (void)out_size;
    (void)Wkt; (void)Wvt;

    dim3 tb(32, 8, 1);
    wcvt_all<<<dim3(12300), tb, 0, stream>>>(Wq, Wk, Wv, Wo, W1, W2, bq, bk, bv,
                                             Wqt, Wot, W1t, W2t, bqkv);

    ln_kernel<<<Mrows, 256, 0, stream>>>(x, ln1g, ln1b, ybuf);

    // fused QKV projection: [8192,1024] @ [1024,3072]
    gemm8p128<0><<<dim3((Mrows / 128) * (QS / 256)), 512, 0, stream>>>(ybuf, Wqt, bqkv, nullptr, qkvb, QS, H);

    attn_kernel<<<dim3(Bb * NH * (S / 128)), 512, 0, stream>>>(qkvb, ab, ob);

    // Wo + residual: [8192,1024] @ [1024,1024] -> f32 d_out
    gemm8p128<2><<<dim3((Mrows / 128) * (H / 256)), 512, 0, stream>>>(ob, Wot, bo, x, d_out, H, H);

    ln_kernel<<<Mrows, 256, 0, stream>>>((const float*)d_out, ln2g, ln2b, ybuf);

    // FFN1: [8192,1024] @ [1024,4096] + gelu
    gemm8p<1><<<dim3((Mrows / 256) * (FF / 256)), 512, 0, stream>>>(ybuf, W1t, b1, hb, FF, H);

    // FFN2 + residual: [8192,4096] @ [4096,1024] -> f32 d_out
    gemm8p128<2><<<dim3((Mrows / 128) * (H / 256)), 512, 0, stream>>>(hb, W2t, b2, (const float*)d_out, d_out, H, FF);
}